// Round 9
// baseline (806.408 us; speedup 1.0000x reference)
//
#include <hip/hip_runtime.h>

typedef unsigned int uint32;
typedef unsigned long long uint64;
typedef unsigned short ushortT;
typedef __attribute__((ext_vector_type(8))) short short8;
typedef __attribute__((ext_vector_type(4))) short short4v;
typedef __attribute__((ext_vector_type(4))) float floatx4;

#define DEV static __device__ __forceinline__

#define NN 2048
#define CC 64
#define KK 20

DEV float bf2f(ushortT h) {
  union { uint32 u; float f; } c; c.u = ((uint32)h) << 16; return c.f;
}
DEV ushortT f2bf(float f) {
  union { float f; uint32 u; } c; c.f = f;
  uint32 r = c.u + 0x7FFFu + ((c.u >> 16) & 1u);   // RNE
  return (ushortT)(r >> 16);
}
DEV void split2(float v, ushortT& h, ushortT& l) {
  h = f2bf(v);
  l = f2bf(v - bf2f(h));
}

// ---------------------------------------------------------------- K0: sq norms (f32)
__global__ void k_sq(const float* __restrict__ x, float* __restrict__ sq) {
  int p = blockIdx.x * 256 + threadIdx.x;
  const float4* row = (const float4*)(x + (size_t)p * CC);
  float s = 0.f;
#pragma unroll
  for (int q = 0; q < 16; ++q) {
    float4 v = row[q];
    s += v.x * v.x + v.y * v.y + v.z * v.z + v.w * v.w;
  }
  sq[p] = s;
}

// ---------------------------------------------------------------- K1: KNN stage 1
// MFMA approx distances -> dense 64x128 key tile in LDS (no atomics/queues).
// 4 owner threads/point keep register top-20 of their 32-column subsets,
// inserting only keys < tau (tau = shfl-min over the 4 owners' 20th key; always
// >= true 20th). Union of 4x20 j-indices written as u16 candidates.
__launch_bounds__(256, 3)
__global__ void k_knn(const float* __restrict__ x, const float* __restrict__ sq,
                      ushortT* __restrict__ cand) {
  const int b  = blockIdx.y;
  const int i0 = blockIdx.x * 64;
  const int t  = threadIdx.x;
  const int l  = t & 63, wv = t >> 6;
  const int la = l & 15, quad = l >> 4;
  const int pp = t >> 2, ss = t & 3;          // owner mapping: point, subset

  __shared__ __align__(16) char sm[52992];
  ushortT (*sXj)[72]  = (ushortT(*)[72])(sm);            // 18432
  uint32  (*sKey)[132]= (uint32(*)[132])(sm + 18432);    // 33792 -> 52224
  float*   sSqi       = (float*)(sm + 52224);            // 256
  float*   sSqj       = (float*)(sm + 52480);            // 512 -> 52992

  const float* xb = x + ((size_t)b * NN) * CC;

  const int mt0 = (wv & 1) * 2;
  const int nt0 = (wv >> 1) * 4;

  // A-fragments straight from global into registers (Xi never hits LDS)
  short8 afrag[2][2];
#pragma unroll
  for (int m = 0; m < 2; ++m) {
    const float* rowp = xb + (size_t)(i0 + (mt0 + m) * 16 + la) * CC;
#pragma unroll
    for (int ks = 0; ks < 2; ++ks) {
      int kof = ks * 32 + quad * 8;
      float4 v0 = *(const float4*)(rowp + kof);
      float4 v1 = *(const float4*)(rowp + kof + 4);
      short8 f;
      f[0] = (short)f2bf(v0.x); f[1] = (short)f2bf(v0.y);
      f[2] = (short)f2bf(v0.z); f[3] = (short)f2bf(v0.w);
      f[4] = (short)f2bf(v1.x); f[5] = (short)f2bf(v1.y);
      f[6] = (short)f2bf(v1.z); f[7] = (short)f2bf(v1.w);
      afrag[m][ks] = f;
    }
  }
  if (t < 64) sSqi[t] = sq[b * NN + i0 + t];

  // stage tile 0
  for (int e = t; e < 2048; e += 256) {
    int r = e >> 4, c4 = (e & 15) * 4;
    float4 v = ((const float4*)(xb + (size_t)r * CC))[e & 15];
    short4v h;
    h.x = (short)f2bf(v.x); h.y = (short)f2bf(v.y);
    h.z = (short)f2bf(v.z); h.w = (short)f2bf(v.w);
    *(short4v*)&sXj[r][c4] = h;
  }
  if (t < 128) sSqj[t] = sq[b * NN + t];

  uint32 lst[KK];
#pragma unroll
  for (int s = 0; s < KK; ++s) lst[s] = 0xFFFFFFFFu;
  uint32 tau = 0xFFFFFFFFu;

  __syncthreads();

  for (int jt = 0; jt < 16; ++jt) {
    const int j0 = jt * 128;

    floatx4 acc[2][4];
#pragma unroll
    for (int m = 0; m < 2; ++m)
#pragma unroll
      for (int n = 0; n < 4; ++n) acc[m][n] = (floatx4){0.f, 0.f, 0.f, 0.f};

#pragma unroll
    for (int ks = 0; ks < 2; ++ks) {
      int kof = ks * 32 + quad * 8;
#pragma unroll
      for (int n = 0; n < 4; ++n) {
        short8 bv = *(const short8*)&sXj[(nt0 + n) * 16 + la][kof];
        acc[0][n] = __builtin_amdgcn_mfma_f32_16x16x32_bf16(afrag[0][ks], bv, acc[0][n], 0, 0, 0);
        acc[1][n] = __builtin_amdgcn_mfma_f32_16x16x32_bf16(afrag[1][ks], bv, acc[1][n], 0, 0, 0);
      }
    }

    // dense key write (fixed pattern, 2-way banks)
#pragma unroll
    for (int m = 0; m < 2; ++m) {
#pragma unroll
      for (int n = 0; n < 4; ++n) {
        int jl = (nt0 + n) * 16 + la;
        float dj = sSqj[jl];
        uint32 jg = (uint32)(j0 + jl);
#pragma unroll
        for (int rg = 0; rg < 4; ++rg) {
          int il = (mt0 + m) * 16 + quad * 4 + rg;
          float d = fmaxf(sSqi[il] + dj - 2.0f * acc[m][n][rg], 0.f);
          sKey[il][jl] = (__float_as_uint(d) & 0xFFFFF800u) | jg;
        }
      }
    }
    __syncthreads();

    // drain own 32-column subset; insert only if < tau
#pragma unroll
    for (int k = 0; k < 32; ++k) {
      uint32 c = sKey[pp][ss + 4 * k];
      if (c < tau) {
        uint32 cur = c;
#pragma unroll
        for (int s = 0; s < KK; ++s) {
          uint32 lo = min(lst[s], cur);
          cur = max(lst[s], cur);
          lst[s] = lo;
        }
      }
    }

    // stage next tile (overlaps drain; barrier below protects MFMA)
    if (jt < 15) {
      const int jn = (jt + 1) * 128;
      for (int e = t; e < 2048; e += 256) {
        int r = e >> 4, c4 = (e & 15) * 4;
        float4 v = ((const float4*)(xb + (size_t)(jn + r) * CC))[e & 15];
        short4v h;
        h.x = (short)f2bf(v.x); h.y = (short)f2bf(v.y);
        h.z = (short)f2bf(v.z); h.w = (short)f2bf(v.w);
        *(short4v*)&sXj[r][c4] = h;
      }
      if (t < 128) sSqj[t] = sq[b * NN + jn + t];
    }

    // tau = min over the point's 4 owner lanes (adjacent lanes) of lst[19]
    uint32 m19 = lst[KK - 1];
    m19 = min(m19, (uint32)__shfl_xor((int)m19, 1));
    m19 = min(m19, (uint32)__shfl_xor((int)m19, 2));
    tau = m19;
    __syncthreads();
  }

  // emit 80 candidates/point (u16 j)
  size_t base = ((size_t)(b * NN + i0 + pp)) * 80 + ss * KK;
#pragma unroll
  for (int s = 0; s < KK; ++s) cand[base + s] = (ushortT)(lst[s] & 2047u);
}

// ---------------------------------------------------------------- K1b: exact f64 rerank
// 16-lane groups compute exact sum((xi-xj)^2) in f64 for 80 cands/point;
// packed u64 keys in LDS; 64 spread threads select final top-20.
__global__ void k_rerank(const float* __restrict__ x, const ushortT* __restrict__ cand,
                         int* __restrict__ idxout) {
  const int b  = blockIdx.y;
  const int i0 = blockIdx.x * 64;
  const int t  = threadIdx.x;
  const int grp = t >> 4, lg = t & 15;
  const int pp = t >> 2, ss = t & 3;

  __shared__ uint64 sK64[64][81];

  const float* xb = x + ((size_t)b * NN) * CC;

  for (int p = 0; p < 64; ++p) {
    float4 vi = ((const float4*)(xb + (size_t)(i0 + p) * CC))[lg];
    size_t cbase = ((size_t)(b * NN + i0 + p)) * 80;
    for (int q = grp; q < 80; q += 16) {
      int j = (int)cand[cbase + q];
      float4 vj = ((const float4*)(xb + (size_t)j * CC))[lg];
      double d;
      {
        double d0 = (double)vi.x - (double)vj.x;
        double d1 = (double)vi.y - (double)vj.y;
        double d2 = (double)vi.z - (double)vj.z;
        double d3 = (double)vi.w - (double)vj.w;
        d = d0 * d0 + d1 * d1 + d2 * d2 + d3 * d3;
      }
#pragma unroll
      for (int off = 8; off > 0; off >>= 1)
        d += __shfl_xor(d, off, 16);
      if (lg == 0) {
        uint64 bits = (uint64)__double_as_longlong(d);    // d >= 0: order-preserving
        sK64[p][q] = (bits & ~2047ULL) | (uint64)j;
      }
    }
  }
  __syncthreads();

  if (ss == 0) {                                          // 64 threads spread over 4 waves
    uint64 bl[KK];
#pragma unroll
    for (int s = 0; s < KK; ++s) bl[s] = ~0ULL;
    for (int q = 0; q < 80; ++q) {
      uint64 c = sK64[pp][q];
      if (c < bl[KK - 1]) {
        uint64 cur = c;
#pragma unroll
        for (int s = 0; s < KK; ++s) {
          uint64 lo = bl[s] < cur ? bl[s] : cur;
          cur = bl[s] < cur ? cur : bl[s];
          bl[s] = lo;
        }
      }
    }
    size_t base = ((size_t)(b * NN + i0 + pp)) * KK;
#pragma unroll
    for (int s = 0; s < KK; ++s) idxout[base + s] = (int)(bl[s] & 2047ULL);
  }
}

// ---------------------------------------------------------------- K2: edge MLP + max-agg (near-f32-exact)
__launch_bounds__(256, 1)
__global__ void k_mlp(const float* __restrict__ x, const int* __restrict__ idx,
                      const float* __restrict__ w1, const float* __restrict__ b1,
                      const float* __restrict__ w2, const float* __restrict__ b2,
                      const float* __restrict__ w3, const float* __restrict__ b3,
                      float* __restrict__ agg) {
  const int b  = blockIdx.y;
  const int i0 = blockIdx.x * 8;
  const int t  = threadIdx.x;
  const int l  = t & 63, wv = t >> 6;
  const int la = l & 15, quad = l >> 4;
  const int wm = wv >> 1, wn = wv & 1;

  __shared__ __align__(16) char sm[152448];
  ushortT (*sW1)[136] = (ushortT(*)[136])(sm + 0);
  ushortT (*sW2)[72]  = (ushortT(*)[72])(sm + 17408);
  ushortT (*sW3)[72]  = (ushortT(*)[72])(sm + 26624);
  ushortT (*sXi)[72]  = (ushortT(*)[72])(sm + 35840);
  ushortT (*sDH)[72]  = (ushortT(*)[72])(sm + 58880);
  ushortT (*sDL)[72]  = (ushortT(*)[72])(sm + 81920);
  ushortT (*sH1H)[72] = (ushortT(*)[72])(sm + 104960);
  ushortT (*sH1L)[72] = (ushortT(*)[72])(sm + 128000);
  float   (*sH3)[68]  = (float(*)[68])  (sm + 104960);
  float* sB1 = (float*)(sm + 151040);
  float* sB2 = (float*)(sm + 151296);
  float* sB3 = (float*)(sm + 151552);
  int*   sJ  = (int*)  (sm + 151808);

  for (int e = t; e < 8192; e += 256) {
    int k = e >> 6, n = e & 63;
    sW1[n][k] = f2bf(w1[e]);
  }
  for (int e = t; e < 4096; e += 256) {
    int k = e >> 6, n = e & 63;
    sW2[n][k] = f2bf(w2[e]);
    sW3[n][k] = f2bf(w3[e]);
  }
  if (t < 64) { sB1[t] = b1[t]; sB2[t] = b2[t]; sB3[t] = b3[t]; }
  if (t < 160) {
    int p = t / 20, kk = t - p * 20;
    int v = idx[((size_t)(b * NN + i0 + p)) * KK + kk];
    v = v < 0 ? 0 : (v > (NN - 1) ? (NN - 1) : v);
    sJ[t] = v;
  }
  __syncthreads();

  const float* xb = x + ((size_t)b * NN) * CC;
  for (int e = t; e < 2560; e += 256) {
    int r = e >> 4, c4g = e & 15, c4 = c4g * 4;
    int p = r / 20;
    float4 vi = ((const float4*)(xb + (size_t)(i0 + p) * CC))[c4g];
    float4 vj = ((const float4*)(xb + (size_t)sJ[r] * CC))[c4g];
    short4v hi, dh, dl;
    ushortT hh, ll;
    hi.x = (short)f2bf(vi.x); hi.y = (short)f2bf(vi.y);
    hi.z = (short)f2bf(vi.z); hi.w = (short)f2bf(vi.w);
    split2(vj.x - vi.x, hh, ll); dh.x = (short)hh; dl.x = (short)ll;
    split2(vj.y - vi.y, hh, ll); dh.y = (short)hh; dl.y = (short)ll;
    split2(vj.z - vi.z, hh, ll); dh.z = (short)hh; dl.z = (short)ll;
    split2(vj.w - vi.w, hh, ll); dh.w = (short)hh; dl.w = (short)ll;
    *(short4v*)&sXi[r][c4] = hi;
    *(short4v*)&sDH[r][c4] = dh;
    *(short4v*)&sDL[r][c4] = dl;
  }
  __syncthreads();

  // ---- layer 1
  {
    short8 bA[2][2], bB[2][2];
#pragma unroll
    for (int n2 = 0; n2 < 2; ++n2)
#pragma unroll
      for (int ks = 0; ks < 2; ++ks) {
        bA[n2][ks] = *(const short8*)&sW1[(wn * 2 + n2) * 16 + la][ks * 32 + quad * 8];
        bB[n2][ks] = *(const short8*)&sW1[(wn * 2 + n2) * 16 + la][64 + ks * 32 + quad * 8];
      }
    for (int m5 = 0; m5 < 5; ++m5) {
      int mt = wm * 5 + m5;
      floatx4 a0 = (floatx4){0.f,0.f,0.f,0.f}, a1 = (floatx4){0.f,0.f,0.f,0.f};
#pragma unroll
      for (int ks = 0; ks < 2; ++ks) {
        int kof = ks * 32 + quad * 8;
        short8 aXi = *(const short8*)&sXi[mt * 16 + la][kof];
        short8 aDH = *(const short8*)&sDH[mt * 16 + la][kof];
        short8 aDL = *(const short8*)&sDL[mt * 16 + la][kof];
        a0 = __builtin_amdgcn_mfma_f32_16x16x32_bf16(aXi, bA[0][ks], a0, 0, 0, 0);
        a0 = __builtin_amdgcn_mfma_f32_16x16x32_bf16(aDH, bB[0][ks], a0, 0, 0, 0);
        a0 = __builtin_amdgcn_mfma_f32_16x16x32_bf16(aDL, bB[0][ks], a0, 0, 0, 0);
        a1 = __builtin_amdgcn_mfma_f32_16x16x32_bf16(aXi, bA[1][ks], a1, 0, 0, 0);
        a1 = __builtin_amdgcn_mfma_f32_16x16x32_bf16(aDH, bB[1][ks], a1, 0, 0, 0);
        a1 = __builtin_amdgcn_mfma_f32_16x16x32_bf16(aDL, bB[1][ks], a1, 0, 0, 0);
      }
      int n0c = (wn * 2) * 16 + la, n1c = (wn * 2 + 1) * 16 + la;
#pragma unroll
      for (int rg = 0; rg < 4; ++rg) {
        int r = mt * 16 + quad * 4 + rg;
        ushortT hh, ll;
        split2(fmaxf(a0[rg] + sB1[n0c], 0.f), hh, ll);
        sH1H[r][n0c] = hh; sH1L[r][n0c] = ll;
        split2(fmaxf(a1[rg] + sB1[n1c], 0.f), hh, ll);
        sH1H[r][n1c] = hh; sH1L[r][n1c] = ll;
      }
    }
  }
  __syncthreads();

  // ---- layer 2
  ushortT (*sH2H)[72] = sXi;
  ushortT (*sH2L)[72] = sDH;
  {
    short8 bf[2][2];
#pragma unroll
    for (int n2 = 0; n2 < 2; ++n2)
#pragma unroll
      for (int ks = 0; ks < 2; ++ks)
        bf[n2][ks] = *(const short8*)&sW2[(wn * 2 + n2) * 16 + la][ks * 32 + quad * 8];
    for (int m5 = 0; m5 < 5; ++m5) {
      int mt = wm * 5 + m5;
      floatx4 a0 = (floatx4){0.f,0.f,0.f,0.f}, a1 = (floatx4){0.f,0.f,0.f,0.f};
#pragma unroll
      for (int ks = 0; ks < 2; ++ks) {
        int kof = ks * 32 + quad * 8;
        short8 aH = *(const short8*)&sH1H[mt * 16 + la][kof];
        short8 aL = *(const short8*)&sH1L[mt * 16 + la][kof];
        a0 = __builtin_amdgcn_mfma_f32_16x16x32_bf16(aH, bf[0][ks], a0, 0, 0, 0);
        a0 = __builtin_amdgcn_mfma_f32_16x16x32_bf16(aL, bf[0][ks], a0, 0, 0, 0);
        a1 = __builtin_amdgcn_mfma_f32_16x16x32_bf16(aH, bf[1][ks], a1, 0, 0, 0);
        a1 = __builtin_amdgcn_mfma_f32_16x16x32_bf16(aL, bf[1][ks], a1, 0, 0, 0);
      }
      int n0c = (wn * 2) * 16 + la, n1c = (wn * 2 + 1) * 16 + la;
#pragma unroll
      for (int rg = 0; rg < 4; ++rg) {
        int r = mt * 16 + quad * 4 + rg;
        ushortT hh, ll;
        split2(fmaxf(a0[rg] + sB2[n0c], 0.f), hh, ll);
        sH2H[r][n0c] = hh; sH2L[r][n0c] = ll;
        split2(fmaxf(a1[rg] + sB2[n1c], 0.f), hh, ll);
        sH2H[r][n1c] = hh; sH2L[r][n1c] = ll;
      }
    }
  }
  __syncthreads();

  // ---- layer 3
  {
    short8 bf[2][2];
#pragma unroll
    for (int n2 = 0; n2 < 2; ++n2)
#pragma unroll
      for (int ks = 0; ks < 2; ++ks)
        bf[n2][ks] = *(const short8*)&sW3[(wn * 2 + n2) * 16 + la][ks * 32 + quad * 8];
    for (int m5 = 0; m5 < 5; ++m5) {
      int mt = wm * 5 + m5;
      floatx4 a0 = (floatx4){0.f,0.f,0.f,0.f}, a1 = (floatx4){0.f,0.f,0.f,0.f};
#pragma unroll
      for (int ks = 0; ks < 2; ++ks) {
        int kof = ks * 32 + quad * 8;
        short8 aH = *(const short8*)&sH2H[mt * 16 + la][kof];
        short8 aL = *(const short8*)&sH2L[mt * 16 + la][kof];
        a0 = __builtin_amdgcn_mfma_f32_16x16x32_bf16(aH, bf[0][ks], a0, 0, 0, 0);
        a0 = __builtin_amdgcn_mfma_f32_16x16x32_bf16(aL, bf[0][ks], a0, 0, 0, 0);
        a1 = __builtin_amdgcn_mfma_f32_16x16x32_bf16(aH, bf[1][ks], a1, 0, 0, 0);
        a1 = __builtin_amdgcn_mfma_f32_16x16x32_bf16(aL, bf[1][ks], a1, 0, 0, 0);
      }
      int n0c = (wn * 2) * 16 + la, n1c = (wn * 2 + 1) * 16 + la;
#pragma unroll
      for (int rg = 0; rg < 4; ++rg) {
        int r = mt * 16 + quad * 4 + rg;
        sH3[r][n0c] = a0[rg] + sB3[n0c];
        sH3[r][n1c] = a1[rg] + sB3[n1c];
      }
    }
  }
  __syncthreads();

  for (int e = t; e < 512; e += 256) {
    int p = e >> 6, c = e & 63;
    float m = -3.0e38f;
#pragma unroll
    for (int k = 0; k < KK; ++k) m = fmaxf(m, sH3[p * 20 + k][c]);
    agg[((size_t)(b * NN + i0 + p)) * CC + c] = m;
  }
}

// ---------------------------------------------------------------- K3: SE (f32)
__global__ void k_se(const float* __restrict__ agg, const float* __restrict__ sew1,
                     const float* __restrict__ sew2, float* __restrict__ y) {
  int b = blockIdx.x, t = threadIdx.x;
  int c = t & 63, q = t >> 6;
  __shared__ float part[4][64];
  __shared__ float sv[64];
  __shared__ float hid[4];
  const float* ab = agg + ((size_t)b * NN) * CC;
  float s = 0.f;
  for (int n = q * 512; n < q * 512 + 512; ++n) s += ab[(size_t)n * CC + c];
  part[q][c] = s;
  __syncthreads();
  if (t < 64) sv[t] = (part[0][t] + part[1][t] + part[2][t] + part[3][t]) * (1.f / 2048.f);
  __syncthreads();
  if (t < 4) {
    float a = 0.f;
    for (int cc = 0; cc < 64; ++cc) a += sv[cc] * sew1[cc * 4 + t];
    hid[t] = fmaxf(a, 0.f);
  }
  __syncthreads();
  if (t < 64) {
    float a = 0.f;
#pragma unroll
    for (int h = 0; h < 4; ++h) a += hid[h] * sew2[h * 64 + t];
    y[b * 64 + t] = 1.f / (1.f + expf(-a));
  }
}

// ---------------------------------------------------------------- K4: per-point stats (f32)
__global__ void k_stats(const float* __restrict__ agg, const float* __restrict__ y,
                        float* __restrict__ ycat) {
  int t = threadIdx.x;
  int gid = blockIdx.x * 4 + (t >> 6);
  int l = t & 63;
  int b = gid >> 11, i = gid & 2047;
  float v = agg[(size_t)gid * CC + l] * y[b * 64 + l];
  float s = v, mx = v;
#pragma unroll
  for (int off = 32; off > 0; off >>= 1) {
    s += __shfl_xor(s, off);
    mx = fmaxf(mx, __shfl_xor(mx, off));
  }
  if (l == 0) {
    ycat[b * 2 * NN + i] = s * (1.f / 64.f);
    ycat[b * 2 * NN + NN + i] = mx;
  }
}

// ---------------------------------------------------------------- K5: conv7 att + add (f32 out)
__global__ void k_final(const float* __restrict__ agg, const float* __restrict__ y,
                        const float* __restrict__ ycat, const float* __restrict__ saw,
                        const float* __restrict__ x, float* __restrict__ out) {
  int e = blockIdx.x * 256 + threadIdx.x;
  int ifl = e >> 6, c = e & 63;
  int b = ifl >> 11, i = ifl & 2047;
  float a = 0.f;
#pragma unroll
  for (int w = 0; w < 7; ++w) {
    int ii = i + w - 3;
    if (ii >= 0 && ii < NN) {
      a += ycat[b * 2 * NN + ii] * saw[w];
      a += ycat[b * 2 * NN + NN + ii] * saw[7 + w];
    }
  }
  float att = 1.f / (1.f + expf(-a));
  out[e] = agg[(size_t)ifl * CC + c] * y[b * 64 + c] * att + x[(size_t)e];
}

// ----------------------------------------------------------------
extern "C" void kernel_launch(void* const* d_in, const int* in_sizes, int n_in,
                              void* d_out, int out_size, void* d_ws, size_t ws_size,
                              hipStream_t stream) {
  const float* x    = (const float*)d_in[0];
  const float* w1   = (const float*)d_in[3];
  const float* b1   = (const float*)d_in[4];
  const float* w2   = (const float*)d_in[5];
  const float* b2   = (const float*)d_in[6];
  const float* w3   = (const float*)d_in[7];
  const float* b3   = (const float*)d_in[8];
  const float* sew1 = (const float*)d_in[9];
  const float* sew2 = (const float*)d_in[10];
  const float* saw  = (const float*)d_in[11];
  float* out = (float*)d_out;

  char* ws = (char*)d_ws;
  float*   sq   = (float*)  (ws);                          // 131072 B
  int*     idx  = (int*)    (ws + 131072);                 // 2621440 B
  ushortT* cand = (ushortT*)(ws + 2752512);                // 5242880 B (32768*80 u16)
  float*   agg  = (float*)  (ws + 2752512);                // 8388608 B (ALIASES cand; cand
                                                           // fully consumed by k_rerank
                                                           // before k_mlp writes agg)
  float*   y    = (float*)  (ws + 11141120);               // 4096 B
  float*   ycat = (float*)  (ws + 11145216);               // 262144 B -> total 11407360 B

  k_sq    <<<128,            256, 0, stream>>>(x, sq);
  k_knn   <<<dim3(32, 16),   256, 0, stream>>>(x, sq, cand);
  k_rerank<<<dim3(32, 16),   256, 0, stream>>>(x, cand, idx);
  k_mlp   <<<dim3(256, 16),  256, 0, stream>>>(x, idx, w1, b1, w2, b2, w3, b3, agg);
  k_se    <<<16,             256, 0, stream>>>(agg, sew1, sew2, y);
  k_stats <<<8192,           256, 0, stream>>>(agg, y, ycat);
  k_final <<<8192,           256, 0, stream>>>(agg, y, ycat, saw, x, out);
}

// Round 10
// 634.344 us; speedup vs baseline: 1.2712x; 1.2712x over previous
//
#include <hip/hip_runtime.h>

typedef unsigned int uint32;
typedef unsigned long long uint64;
typedef unsigned short ushortT;
typedef __attribute__((ext_vector_type(8))) short short8;
typedef __attribute__((ext_vector_type(4))) short short4v;
typedef __attribute__((ext_vector_type(4))) float floatx4;

#define DEV static __device__ __forceinline__

#define NN 2048
#define CC 64
#define KK 20

DEV float bf2f(ushortT h) {
  union { uint32 u; float f; } c; c.u = ((uint32)h) << 16; return c.f;
}
DEV ushortT f2bf(float f) {
  union { float f; uint32 u; } c; c.f = f;
  uint32 r = c.u + 0x7FFFu + ((c.u >> 16) & 1u);   // RNE
  return (ushortT)(r >> 16);
}
DEV void split2(float v, ushortT& h, ushortT& l) {
  h = f2bf(v);
  l = f2bf(v - bf2f(h));
}

// ---------------------------------------------------------------- K0: sq norms (f32)
__global__ void k_sq(const float* __restrict__ x, float* __restrict__ sq) {
  int p = blockIdx.x * 256 + threadIdx.x;
  const float4* row = (const float4*)(x + (size_t)p * CC);
  float s = 0.f;
#pragma unroll
  for (int q = 0; q < 16; ++q) {
    float4 v = row[q];
    s += v.x * v.x + v.y * v.y + v.z * v.z + v.w * v.w;
  }
  sq[p] = s;
}

// ---------------------------------------------------------------- K1: KNN stage 1
__launch_bounds__(256, 3)
__global__ void k_knn(const float* __restrict__ x, const float* __restrict__ sq,
                      ushortT* __restrict__ cand) {
  const int b  = blockIdx.y;
  const int i0 = blockIdx.x * 64;
  const int t  = threadIdx.x;
  const int l  = t & 63, wv = t >> 6;
  const int la = l & 15, quad = l >> 4;
  const int pp = t >> 2, ss = t & 3;          // owner mapping: point, subset

  __shared__ __align__(16) char sm[52992];
  ushortT (*sXj)[72]  = (ushortT(*)[72])(sm);            // 18432
  uint32  (*sKey)[132]= (uint32(*)[132])(sm + 18432);    // 33792 -> 52224
  float*   sSqi       = (float*)(sm + 52224);            // 256
  float*   sSqj       = (float*)(sm + 52480);            // 512 -> 52992

  const float* xb = x + ((size_t)b * NN) * CC;

  const int mt0 = (wv & 1) * 2;
  const int nt0 = (wv >> 1) * 4;

  // A-fragments straight from global into registers (Xi never hits LDS)
  short8 afrag[2][2];
#pragma unroll
  for (int m = 0; m < 2; ++m) {
    const float* rowp = xb + (size_t)(i0 + (mt0 + m) * 16 + la) * CC;
#pragma unroll
    for (int ks = 0; ks < 2; ++ks) {
      int kof = ks * 32 + quad * 8;
      float4 v0 = *(const float4*)(rowp + kof);
      float4 v1 = *(const float4*)(rowp + kof + 4);
      short8 f;
      f[0] = (short)f2bf(v0.x); f[1] = (short)f2bf(v0.y);
      f[2] = (short)f2bf(v0.z); f[3] = (short)f2bf(v0.w);
      f[4] = (short)f2bf(v1.x); f[5] = (short)f2bf(v1.y);
      f[6] = (short)f2bf(v1.z); f[7] = (short)f2bf(v1.w);
      afrag[m][ks] = f;
    }
  }
  if (t < 64) sSqi[t] = sq[b * NN + i0 + t];

  // stage tile 0
  for (int e = t; e < 2048; e += 256) {
    int r = e >> 4, c4 = (e & 15) * 4;
    float4 v = ((const float4*)(xb + (size_t)r * CC))[e & 15];
    short4v h;
    h.x = (short)f2bf(v.x); h.y = (short)f2bf(v.y);
    h.z = (short)f2bf(v.z); h.w = (short)f2bf(v.w);
    *(short4v*)&sXj[r][c4] = h;
  }
  if (t < 128) sSqj[t] = sq[b * NN + t];

  uint32 lst[KK];
#pragma unroll
  for (int s = 0; s < KK; ++s) lst[s] = 0xFFFFFFFFu;
  uint32 tau = 0xFFFFFFFFu;

  __syncthreads();

  for (int jt = 0; jt < 16; ++jt) {
    const int j0 = jt * 128;

    floatx4 acc[2][4];
#pragma unroll
    for (int m = 0; m < 2; ++m)
#pragma unroll
      for (int n = 0; n < 4; ++n) acc[m][n] = (floatx4){0.f, 0.f, 0.f, 0.f};

#pragma unroll
    for (int ks = 0; ks < 2; ++ks) {
      int kof = ks * 32 + quad * 8;
#pragma unroll
      for (int n = 0; n < 4; ++n) {
        short8 bv = *(const short8*)&sXj[(nt0 + n) * 16 + la][kof];
        acc[0][n] = __builtin_amdgcn_mfma_f32_16x16x32_bf16(afrag[0][ks], bv, acc[0][n], 0, 0, 0);
        acc[1][n] = __builtin_amdgcn_mfma_f32_16x16x32_bf16(afrag[1][ks], bv, acc[1][n], 0, 0, 0);
      }
    }

    // dense key write (fixed pattern, 2-way banks)
#pragma unroll
    for (int m = 0; m < 2; ++m) {
#pragma unroll
      for (int n = 0; n < 4; ++n) {
        int jl = (nt0 + n) * 16 + la;
        float dj = sSqj[jl];
        uint32 jg = (uint32)(j0 + jl);
#pragma unroll
        for (int rg = 0; rg < 4; ++rg) {
          int il = (mt0 + m) * 16 + quad * 4 + rg;
          float d = fmaxf(sSqi[il] + dj - 2.0f * acc[m][n][rg], 0.f);
          sKey[il][jl] = (__float_as_uint(d) & 0xFFFFF800u) | jg;
        }
      }
    }
    __syncthreads();

    // drain own 32-column subset; insert only if < tau
#pragma unroll
    for (int k = 0; k < 32; ++k) {
      uint32 c = sKey[pp][ss + 4 * k];
      if (c < tau) {
        uint32 cur = c;
#pragma unroll
        for (int s = 0; s < KK; ++s) {
          uint32 lo = min(lst[s], cur);
          cur = max(lst[s], cur);
          lst[s] = lo;
        }
      }
    }

    // stage next tile (overlaps drain; barrier below protects MFMA)
    if (jt < 15) {
      const int jn = (jt + 1) * 128;
      for (int e = t; e < 2048; e += 256) {
        int r = e >> 4, c4 = (e & 15) * 4;
        float4 v = ((const float4*)(xb + (size_t)(jn + r) * CC))[e & 15];
        short4v h;
        h.x = (short)f2bf(v.x); h.y = (short)f2bf(v.y);
        h.z = (short)f2bf(v.z); h.w = (short)f2bf(v.w);
        *(short4v*)&sXj[r][c4] = h;
      }
      if (t < 128) sSqj[t] = sq[b * NN + jn + t];
    }

    // tau = min over the point's 4 owner lanes (adjacent lanes) of lst[19]
    uint32 m19 = lst[KK - 1];
    m19 = min(m19, (uint32)__shfl_xor((int)m19, 1));
    m19 = min(m19, (uint32)__shfl_xor((int)m19, 2));
    tau = m19;
    __syncthreads();
  }

  // emit 80 candidates/point (u16 j)
  size_t base = ((size_t)(b * NN + i0 + pp)) * 80 + ss * KK;
#pragma unroll
  for (int s = 0; s < KK; ++s) cand[base + s] = (ushortT)(lst[s] & 2047u);
}

// ---------------------------------------------------------------- K1b: exact f64 rerank
// 16-lane groups; p unrolled x2, q fully unrolled (5/group) -> 10 independent
// latency chains in flight (loads, f64 fma, shfl-reduce rounds all interleaved).
__launch_bounds__(256, 3)
__global__ void k_rerank(const float* __restrict__ x, const ushortT* __restrict__ cand,
                         int* __restrict__ idxout) {
  const int b  = blockIdx.y;
  const int i0 = blockIdx.x * 64;
  const int t  = threadIdx.x;
  const int grp = t >> 4, lg = t & 15;
  const int pp = t >> 2, ss = t & 3;

  __shared__ uint64 sK64[64][81];

  const float* xb = x + ((size_t)b * NN) * CC;

  for (int p = 0; p < 64; p += 2) {
    float4 vi0 = ((const float4*)(xb + (size_t)(i0 + p    ) * CC))[lg];
    float4 vi1 = ((const float4*)(xb + (size_t)(i0 + p + 1) * CC))[lg];
    size_t cb0 = ((size_t)(b * NN + i0 + p)) * 80;
    size_t cb1 = cb0 + 80;

    int j0[5], j1[5];
#pragma unroll
    for (int u = 0; u < 5; ++u) {
      int q = grp + 16 * u;
      j0[u] = (int)cand[cb0 + q];
      j1[u] = (int)cand[cb1 + q];
    }

    double d0[5], d1[5];
#pragma unroll
    for (int u = 0; u < 5; ++u) {
      float4 vj0 = ((const float4*)(xb + (size_t)j0[u] * CC))[lg];
      float4 vj1 = ((const float4*)(xb + (size_t)j1[u] * CC))[lg];
      double a0 = (double)vi0.x - (double)vj0.x;
      double a1 = (double)vi0.y - (double)vj0.y;
      double a2 = (double)vi0.z - (double)vj0.z;
      double a3 = (double)vi0.w - (double)vj0.w;
      d0[u] = a0 * a0 + a1 * a1 + a2 * a2 + a3 * a3;
      double c0 = (double)vi1.x - (double)vj1.x;
      double c1 = (double)vi1.y - (double)vj1.y;
      double c2 = (double)vi1.z - (double)vj1.z;
      double c3 = (double)vi1.w - (double)vj1.w;
      d1[u] = c0 * c0 + c1 * c1 + c2 * c2 + c3 * c3;
    }

#pragma unroll
    for (int off = 8; off > 0; off >>= 1) {
#pragma unroll
      for (int u = 0; u < 5; ++u) {
        d0[u] += __shfl_xor(d0[u], off, 16);
        d1[u] += __shfl_xor(d1[u], off, 16);
      }
    }

    if (lg == 0) {
#pragma unroll
      for (int u = 0; u < 5; ++u) {
        int q = grp + 16 * u;
        uint64 b0 = (uint64)__double_as_longlong(d0[u]);
        uint64 b1 = (uint64)__double_as_longlong(d1[u]);
        sK64[p    ][q] = (b0 & ~2047ULL) | (uint64)j0[u];
        sK64[p + 1][q] = (b1 & ~2047ULL) | (uint64)j1[u];
      }
    }
  }
  __syncthreads();

  if (ss == 0) {                                          // 64 threads spread over 4 waves
    uint64 bl[KK];
#pragma unroll
    for (int s = 0; s < KK; ++s) bl[s] = ~0ULL;
    for (int q = 0; q < 80; ++q) {
      uint64 c = sK64[pp][q];
      if (c < bl[KK - 1]) {
        uint64 cur = c;
#pragma unroll
        for (int s = 0; s < KK; ++s) {
          uint64 lo = bl[s] < cur ? bl[s] : cur;
          cur = bl[s] < cur ? cur : bl[s];
          bl[s] = lo;
        }
      }
    }
    size_t base = ((size_t)(b * NN + i0 + pp)) * KK;
#pragma unroll
    for (int s = 0; s < KK; ++s) idxout[base + s] = (int)(bl[s] & 2047ULL);
  }
}

// ---------------------------------------------------------------- K2: edge MLP + max-agg (near-f32-exact)
__launch_bounds__(256, 1)
__global__ void k_mlp(const float* __restrict__ x, const int* __restrict__ idx,
                      const float* __restrict__ w1, const float* __restrict__ b1,
                      const float* __restrict__ w2, const float* __restrict__ b2,
                      const float* __restrict__ w3, const float* __restrict__ b3,
                      float* __restrict__ agg) {
  const int b  = blockIdx.y;
  const int i0 = blockIdx.x * 8;
  const int t  = threadIdx.x;
  const int l  = t & 63, wv = t >> 6;
  const int la = l & 15, quad = l >> 4;
  const int wm = wv >> 1, wn = wv & 1;

  __shared__ __align__(16) char sm[152448];
  ushortT (*sW1)[136] = (ushortT(*)[136])(sm + 0);
  ushortT (*sW2)[72]  = (ushortT(*)[72])(sm + 17408);
  ushortT (*sW3)[72]  = (ushortT(*)[72])(sm + 26624);
  ushortT (*sXi)[72]  = (ushortT(*)[72])(sm + 35840);
  ushortT (*sDH)[72]  = (ushortT(*)[72])(sm + 58880);
  ushortT (*sDL)[72]  = (ushortT(*)[72])(sm + 81920);
  ushortT (*sH1H)[72] = (ushortT(*)[72])(sm + 104960);
  ushortT (*sH1L)[72] = (ushortT(*)[72])(sm + 128000);
  float   (*sH3)[68]  = (float(*)[68])  (sm + 104960);
  float* sB1 = (float*)(sm + 151040);
  float* sB2 = (float*)(sm + 151296);
  float* sB3 = (float*)(sm + 151552);
  int*   sJ  = (int*)  (sm + 151808);

  for (int e = t; e < 8192; e += 256) {
    int k = e >> 6, n = e & 63;
    sW1[n][k] = f2bf(w1[e]);
  }
  for (int e = t; e < 4096; e += 256) {
    int k = e >> 6, n = e & 63;
    sW2[n][k] = f2bf(w2[e]);
    sW3[n][k] = f2bf(w3[e]);
  }
  if (t < 64) { sB1[t] = b1[t]; sB2[t] = b2[t]; sB3[t] = b3[t]; }
  if (t < 160) {
    int p = t / 20, kk = t - p * 20;
    int v = idx[((size_t)(b * NN + i0 + p)) * KK + kk];
    v = v < 0 ? 0 : (v > (NN - 1) ? (NN - 1) : v);
    sJ[t] = v;
  }
  __syncthreads();

  const float* xb = x + ((size_t)b * NN) * CC;
  for (int e = t; e < 2560; e += 256) {
    int r = e >> 4, c4g = e & 15, c4 = c4g * 4;
    int p = r / 20;
    float4 vi = ((const float4*)(xb + (size_t)(i0 + p) * CC))[c4g];
    float4 vj = ((const float4*)(xb + (size_t)sJ[r] * CC))[c4g];
    short4v hi, dh, dl;
    ushortT hh, ll;
    hi.x = (short)f2bf(vi.x); hi.y = (short)f2bf(vi.y);
    hi.z = (short)f2bf(vi.z); hi.w = (short)f2bf(vi.w);
    split2(vj.x - vi.x, hh, ll); dh.x = (short)hh; dl.x = (short)ll;
    split2(vj.y - vi.y, hh, ll); dh.y = (short)hh; dl.y = (short)ll;
    split2(vj.z - vi.z, hh, ll); dh.z = (short)hh; dl.z = (short)ll;
    split2(vj.w - vi.w, hh, ll); dh.w = (short)hh; dl.w = (short)ll;
    *(short4v*)&sXi[r][c4] = hi;
    *(short4v*)&sDH[r][c4] = dh;
    *(short4v*)&sDL[r][c4] = dl;
  }
  __syncthreads();

  // ---- layer 1
  {
    short8 bA[2][2], bB[2][2];
#pragma unroll
    for (int n2 = 0; n2 < 2; ++n2)
#pragma unroll
      for (int ks = 0; ks < 2; ++ks) {
        bA[n2][ks] = *(const short8*)&sW1[(wn * 2 + n2) * 16 + la][ks * 32 + quad * 8];
        bB[n2][ks] = *(const short8*)&sW1[(wn * 2 + n2) * 16 + la][64 + ks * 32 + quad * 8];
      }
    for (int m5 = 0; m5 < 5; ++m5) {
      int mt = wm * 5 + m5;
      floatx4 a0 = (floatx4){0.f,0.f,0.f,0.f}, a1 = (floatx4){0.f,0.f,0.f,0.f};
#pragma unroll
      for (int ks = 0; ks < 2; ++ks) {
        int kof = ks * 32 + quad * 8;
        short8 aXi = *(const short8*)&sXi[mt * 16 + la][kof];
        short8 aDH = *(const short8*)&sDH[mt * 16 + la][kof];
        short8 aDL = *(const short8*)&sDL[mt * 16 + la][kof];
        a0 = __builtin_amdgcn_mfma_f32_16x16x32_bf16(aXi, bA[0][ks], a0, 0, 0, 0);
        a0 = __builtin_amdgcn_mfma_f32_16x16x32_bf16(aDH, bB[0][ks], a0, 0, 0, 0);
        a0 = __builtin_amdgcn_mfma_f32_16x16x32_bf16(aDL, bB[0][ks], a0, 0, 0, 0);
        a1 = __builtin_amdgcn_mfma_f32_16x16x32_bf16(aXi, bA[1][ks], a1, 0, 0, 0);
        a1 = __builtin_amdgcn_mfma_f32_16x16x32_bf16(aDH, bB[1][ks], a1, 0, 0, 0);
        a1 = __builtin_amdgcn_mfma_f32_16x16x32_bf16(aDL, bB[1][ks], a1, 0, 0, 0);
      }
      int n0c = (wn * 2) * 16 + la, n1c = (wn * 2 + 1) * 16 + la;
#pragma unroll
      for (int rg = 0; rg < 4; ++rg) {
        int r = mt * 16 + quad * 4 + rg;
        ushortT hh, ll;
        split2(fmaxf(a0[rg] + sB1[n0c], 0.f), hh, ll);
        sH1H[r][n0c] = hh; sH1L[r][n0c] = ll;
        split2(fmaxf(a1[rg] + sB1[n1c], 0.f), hh, ll);
        sH1H[r][n1c] = hh; sH1L[r][n1c] = ll;
      }
    }
  }
  __syncthreads();

  // ---- layer 2
  ushortT (*sH2H)[72] = sXi;
  ushortT (*sH2L)[72] = sDH;
  {
    short8 bf[2][2];
#pragma unroll
    for (int n2 = 0; n2 < 2; ++n2)
#pragma unroll
      for (int ks = 0; ks < 2; ++ks)
        bf[n2][ks] = *(const short8*)&sW2[(wn * 2 + n2) * 16 + la][ks * 32 + quad * 8];
    for (int m5 = 0; m5 < 5; ++m5) {
      int mt = wm * 5 + m5;
      floatx4 a0 = (floatx4){0.f,0.f,0.f,0.f}, a1 = (floatx4){0.f,0.f,0.f,0.f};
#pragma unroll
      for (int ks = 0; ks < 2; ++ks) {
        int kof = ks * 32 + quad * 8;
        short8 aH = *(const short8*)&sH1H[mt * 16 + la][kof];
        short8 aL = *(const short8*)&sH1L[mt * 16 + la][kof];
        a0 = __builtin_amdgcn_mfma_f32_16x16x32_bf16(aH, bf[0][ks], a0, 0, 0, 0);
        a0 = __builtin_amdgcn_mfma_f32_16x16x32_bf16(aL, bf[0][ks], a0, 0, 0, 0);
        a1 = __builtin_amdgcn_mfma_f32_16x16x32_bf16(aH, bf[1][ks], a1, 0, 0, 0);
        a1 = __builtin_amdgcn_mfma_f32_16x16x32_bf16(aL, bf[1][ks], a1, 0, 0, 0);
      }
      int n0c = (wn * 2) * 16 + la, n1c = (wn * 2 + 1) * 16 + la;
#pragma unroll
      for (int rg = 0; rg < 4; ++rg) {
        int r = mt * 16 + quad * 4 + rg;
        ushortT hh, ll;
        split2(fmaxf(a0[rg] + sB2[n0c], 0.f), hh, ll);
        sH2H[r][n0c] = hh; sH2L[r][n0c] = ll;
        split2(fmaxf(a1[rg] + sB2[n1c], 0.f), hh, ll);
        sH2H[r][n1c] = hh; sH2L[r][n1c] = ll;
      }
    }
  }
  __syncthreads();

  // ---- layer 3
  {
    short8 bf[2][2];
#pragma unroll
    for (int n2 = 0; n2 < 2; ++n2)
#pragma unroll
      for (int ks = 0; ks < 2; ++ks)
        bf[n2][ks] = *(const short8*)&sW3[(wn * 2 + n2) * 16 + la][ks * 32 + quad * 8];
    for (int m5 = 0; m5 < 5; ++m5) {
      int mt = wm * 5 + m5;
      floatx4 a0 = (floatx4){0.f,0.f,0.f,0.f}, a1 = (floatx4){0.f,0.f,0.f,0.f};
#pragma unroll
      for (int ks = 0; ks < 2; ++ks) {
        int kof = ks * 32 + quad * 8;
        short8 aH = *(const short8*)&sH2H[mt * 16 + la][kof];
        short8 aL = *(const short8*)&sH2L[mt * 16 + la][kof];
        a0 = __builtin_amdgcn_mfma_f32_16x16x32_bf16(aH, bf[0][ks], a0, 0, 0, 0);
        a0 = __builtin_amdgcn_mfma_f32_16x16x32_bf16(aL, bf[0][ks], a0, 0, 0, 0);
        a1 = __builtin_amdgcn_mfma_f32_16x16x32_bf16(aH, bf[1][ks], a1, 0, 0, 0);
        a1 = __builtin_amdgcn_mfma_f32_16x16x32_bf16(aL, bf[1][ks], a1, 0, 0, 0);
      }
      int n0c = (wn * 2) * 16 + la, n1c = (wn * 2 + 1) * 16 + la;
#pragma unroll
      for (int rg = 0; rg < 4; ++rg) {
        int r = mt * 16 + quad * 4 + rg;
        sH3[r][n0c] = a0[rg] + sB3[n0c];
        sH3[r][n1c] = a1[rg] + sB3[n1c];
      }
    }
  }
  __syncthreads();

  for (int e = t; e < 512; e += 256) {
    int p = e >> 6, c = e & 63;
    float m = -3.0e38f;
#pragma unroll
    for (int k = 0; k < KK; ++k) m = fmaxf(m, sH3[p * 20 + k][c]);
    agg[((size_t)(b * NN + i0 + p)) * CC + c] = m;
  }
}

// ---------------------------------------------------------------- K3: SE (f32)
__global__ void k_se(const float* __restrict__ agg, const float* __restrict__ sew1,
                     const float* __restrict__ sew2, float* __restrict__ y) {
  int b = blockIdx.x, t = threadIdx.x;
  int c = t & 63, q = t >> 6;
  __shared__ float part[4][64];
  __shared__ float sv[64];
  __shared__ float hid[4];
  const float* ab = agg + ((size_t)b * NN) * CC;
  float s = 0.f;
  for (int n = q * 512; n < q * 512 + 512; ++n) s += ab[(size_t)n * CC + c];
  part[q][c] = s;
  __syncthreads();
  if (t < 64) sv[t] = (part[0][t] + part[1][t] + part[2][t] + part[3][t]) * (1.f / 2048.f);
  __syncthreads();
  if (t < 4) {
    float a = 0.f;
    for (int cc = 0; cc < 64; ++cc) a += sv[cc] * sew1[cc * 4 + t];
    hid[t] = fmaxf(a, 0.f);
  }
  __syncthreads();
  if (t < 64) {
    float a = 0.f;
#pragma unroll
    for (int h = 0; h < 4; ++h) a += hid[h] * sew2[h * 64 + t];
    y[b * 64 + t] = 1.f / (1.f + expf(-a));
  }
}

// ---------------------------------------------------------------- K4: per-point stats (f32)
__global__ void k_stats(const float* __restrict__ agg, const float* __restrict__ y,
                        float* __restrict__ ycat) {
  int t = threadIdx.x;
  int gid = blockIdx.x * 4 + (t >> 6);
  int l = t & 63;
  int b = gid >> 11, i = gid & 2047;
  float v = agg[(size_t)gid * CC + l] * y[b * 64 + l];
  float s = v, mx = v;
#pragma unroll
  for (int off = 32; off > 0; off >>= 1) {
    s += __shfl_xor(s, off);
    mx = fmaxf(mx, __shfl_xor(mx, off));
  }
  if (l == 0) {
    ycat[b * 2 * NN + i] = s * (1.f / 64.f);
    ycat[b * 2 * NN + NN + i] = mx;
  }
}

// ---------------------------------------------------------------- K5: conv7 att + add (f32 out)
__global__ void k_final(const float* __restrict__ agg, const float* __restrict__ y,
                        const float* __restrict__ ycat, const float* __restrict__ saw,
                        const float* __restrict__ x, float* __restrict__ out) {
  int e = blockIdx.x * 256 + threadIdx.x;
  int ifl = e >> 6, c = e & 63;
  int b = ifl >> 11, i = ifl & 2047;
  float a = 0.f;
#pragma unroll
  for (int w = 0; w < 7; ++w) {
    int ii = i + w - 3;
    if (ii >= 0 && ii < NN) {
      a += ycat[b * 2 * NN + ii] * saw[w];
      a += ycat[b * 2 * NN + NN + ii] * saw[7 + w];
    }
  }
  float att = 1.f / (1.f + expf(-a));
  out[e] = agg[(size_t)ifl * CC + c] * y[b * 64 + c] * att + x[(size_t)e];
}

// ----------------------------------------------------------------
extern "C" void kernel_launch(void* const* d_in, const int* in_sizes, int n_in,
                              void* d_out, int out_size, void* d_ws, size_t ws_size,
                              hipStream_t stream) {
  const float* x    = (const float*)d_in[0];
  const float* w1   = (const float*)d_in[3];
  const float* b1   = (const float*)d_in[4];
  const float* w2   = (const float*)d_in[5];
  const float* b2   = (const float*)d_in[6];
  const float* w3   = (const float*)d_in[7];
  const float* b3   = (const float*)d_in[8];
  const float* sew1 = (const float*)d_in[9];
  const float* sew2 = (const float*)d_in[10];
  const float* saw  = (const float*)d_in[11];
  float* out = (float*)d_out;

  char* ws = (char*)d_ws;
  float*   sq   = (float*)  (ws);                          // 131072 B
  int*     idx  = (int*)    (ws + 131072);                 // 2621440 B
  ushortT* cand = (ushortT*)(ws + 2752512);                // 5242880 B (32768*80 u16)
  float*   agg  = (float*)  (ws + 2752512);                // 8388608 B (ALIASES cand; cand
                                                           // fully consumed by k_rerank
                                                           // before k_mlp writes agg)
  float*   y    = (float*)  (ws + 11141120);               // 4096 B
  float*   ycat = (float*)  (ws + 11145216);               // 262144 B -> total 11407360 B

  k_sq    <<<128,            256, 0, stream>>>(x, sq);
  k_knn   <<<dim3(32, 16),   256, 0, stream>>>(x, sq, cand);
  k_rerank<<<dim3(32, 16),   256, 0, stream>>>(x, cand, idx);
  k_mlp   <<<dim3(256, 16),  256, 0, stream>>>(x, idx, w1, b1, w2, b2, w3, b3, agg);
  k_se    <<<16,             256, 0, stream>>>(agg, sew1, sew2, y);
  k_stats <<<8192,           256, 0, stream>>>(agg, y, ycat);
  k_final <<<8192,           256, 0, stream>>>(agg, y, ycat, saw, x, out);
}

// Round 11
// 571.259 us; speedup vs baseline: 1.4116x; 1.1104x over previous
//
#include <hip/hip_runtime.h>

typedef unsigned int uint32;
typedef unsigned long long uint64;
typedef unsigned short ushortT;
typedef __attribute__((ext_vector_type(8))) short short8;
typedef __attribute__((ext_vector_type(4))) short short4v;
typedef __attribute__((ext_vector_type(4))) float floatx4;

#define DEV static __device__ __forceinline__

#define NN 2048
#define CC 64
#define KK 20

DEV float bf2f(ushortT h) {
  union { uint32 u; float f; } c; c.u = ((uint32)h) << 16; return c.f;
}
DEV ushortT f2bf(float f) {
  union { float f; uint32 u; } c; c.f = f;
  uint32 r = c.u + 0x7FFFu + ((c.u >> 16) & 1u);   // RNE
  return (ushortT)(r >> 16);
}
DEV void split2(float v, ushortT& h, ushortT& l) {
  h = f2bf(v);
  l = f2bf(v - bf2f(h));
}
DEV uint32 fmap(float f) {            // monotone f32 -> u32
  uint32 u = __float_as_uint(f);
  return (u & 0x80000000u) ? ~u : (u | 0x80000000u);
}
DEV float funmap(uint32 m) {
  uint32 u = (m & 0x80000000u) ? (m ^ 0x80000000u) : ~m;
  return __uint_as_float(u);
}
DEV short8 ld8(const ushortT* p) {    // 8B-aligned 16B load as two b64
  short4v a = *(const short4v*)p;
  short4v b = *(const short4v*)(p + 4);
  short8 r;
  r[0] = a.x; r[1] = a.y; r[2] = a.z; r[3] = a.w;
  r[4] = b.x; r[5] = b.y; r[6] = b.z; r[7] = b.w;
  return r;
}

// ---------------------------------------------------------------- K0: sq norms (f32)
__global__ void k_sq(const float* __restrict__ x, float* __restrict__ sq) {
  int p = blockIdx.x * 256 + threadIdx.x;
  const float4* row = (const float4*)(x + (size_t)p * CC);
  float s = 0.f;
#pragma unroll
  for (int q = 0; q < 16; ++q) {
    float4 v = row[q];
    s += v.x * v.x + v.y * v.y + v.z * v.z + v.w * v.w;
  }
  sq[p] = s;
}

// ---------------------------------------------------------------- K1: KNN stage 1 (unchanged)
__launch_bounds__(256, 3)
__global__ void k_knn(const float* __restrict__ x, const float* __restrict__ sq,
                      ushortT* __restrict__ cand) {
  const int b  = blockIdx.y;
  const int i0 = blockIdx.x * 64;
  const int t  = threadIdx.x;
  const int l  = t & 63, wv = t >> 6;
  const int la = l & 15, quad = l >> 4;
  const int pp = t >> 2, ss = t & 3;

  __shared__ __align__(16) char sm[52992];
  ushortT (*sXj)[72]  = (ushortT(*)[72])(sm);
  uint32  (*sKey)[132]= (uint32(*)[132])(sm + 18432);
  float*   sSqi       = (float*)(sm + 52224);
  float*   sSqj       = (float*)(sm + 52480);

  const float* xb = x + ((size_t)b * NN) * CC;

  const int mt0 = (wv & 1) * 2;
  const int nt0 = (wv >> 1) * 4;

  short8 afrag[2][2];
#pragma unroll
  for (int m = 0; m < 2; ++m) {
    const float* rowp = xb + (size_t)(i0 + (mt0 + m) * 16 + la) * CC;
#pragma unroll
    for (int ks = 0; ks < 2; ++ks) {
      int kof = ks * 32 + quad * 8;
      float4 v0 = *(const float4*)(rowp + kof);
      float4 v1 = *(const float4*)(rowp + kof + 4);
      short8 f;
      f[0] = (short)f2bf(v0.x); f[1] = (short)f2bf(v0.y);
      f[2] = (short)f2bf(v0.z); f[3] = (short)f2bf(v0.w);
      f[4] = (short)f2bf(v1.x); f[5] = (short)f2bf(v1.y);
      f[6] = (short)f2bf(v1.z); f[7] = (short)f2bf(v1.w);
      afrag[m][ks] = f;
    }
  }
  if (t < 64) sSqi[t] = sq[b * NN + i0 + t];

  for (int e = t; e < 2048; e += 256) {
    int r = e >> 4, c4 = (e & 15) * 4;
    float4 v = ((const float4*)(xb + (size_t)r * CC))[e & 15];
    short4v h;
    h.x = (short)f2bf(v.x); h.y = (short)f2bf(v.y);
    h.z = (short)f2bf(v.z); h.w = (short)f2bf(v.w);
    *(short4v*)&sXj[r][c4] = h;
  }
  if (t < 128) sSqj[t] = sq[b * NN + t];

  uint32 lst[KK];
#pragma unroll
  for (int s = 0; s < KK; ++s) lst[s] = 0xFFFFFFFFu;
  uint32 tau = 0xFFFFFFFFu;

  __syncthreads();

  for (int jt = 0; jt < 16; ++jt) {
    const int j0 = jt * 128;

    floatx4 acc[2][4];
#pragma unroll
    for (int m = 0; m < 2; ++m)
#pragma unroll
      for (int n = 0; n < 4; ++n) acc[m][n] = (floatx4){0.f, 0.f, 0.f, 0.f};

#pragma unroll
    for (int ks = 0; ks < 2; ++ks) {
      int kof = ks * 32 + quad * 8;
#pragma unroll
      for (int n = 0; n < 4; ++n) {
        short8 bv = *(const short8*)&sXj[(nt0 + n) * 16 + la][kof];
        acc[0][n] = __builtin_amdgcn_mfma_f32_16x16x32_bf16(afrag[0][ks], bv, acc[0][n], 0, 0, 0);
        acc[1][n] = __builtin_amdgcn_mfma_f32_16x16x32_bf16(afrag[1][ks], bv, acc[1][n], 0, 0, 0);
      }
    }

#pragma unroll
    for (int m = 0; m < 2; ++m) {
#pragma unroll
      for (int n = 0; n < 4; ++n) {
        int jl = (nt0 + n) * 16 + la;
        float dj = sSqj[jl];
        uint32 jg = (uint32)(j0 + jl);
#pragma unroll
        for (int rg = 0; rg < 4; ++rg) {
          int il = (mt0 + m) * 16 + quad * 4 + rg;
          float d = fmaxf(sSqi[il] + dj - 2.0f * acc[m][n][rg], 0.f);
          sKey[il][jl] = (__float_as_uint(d) & 0xFFFFF800u) | jg;
        }
      }
    }
    __syncthreads();

#pragma unroll
    for (int k = 0; k < 32; ++k) {
      uint32 c = sKey[pp][ss + 4 * k];
      if (c < tau) {
        uint32 cur = c;
#pragma unroll
        for (int s = 0; s < KK; ++s) {
          uint32 lo = min(lst[s], cur);
          cur = max(lst[s], cur);
          lst[s] = lo;
        }
      }
    }

    if (jt < 15) {
      const int jn = (jt + 1) * 128;
      for (int e = t; e < 2048; e += 256) {
        int r = e >> 4, c4 = (e & 15) * 4;
        float4 v = ((const float4*)(xb + (size_t)(jn + r) * CC))[e & 15];
        short4v h;
        h.x = (short)f2bf(v.x); h.y = (short)f2bf(v.y);
        h.z = (short)f2bf(v.z); h.w = (short)f2bf(v.w);
        *(short4v*)&sXj[r][c4] = h;
      }
      if (t < 128) sSqj[t] = sq[b * NN + jn + t];
    }

    uint32 m19 = lst[KK - 1];
    m19 = min(m19, (uint32)__shfl_xor((int)m19, 1));
    m19 = min(m19, (uint32)__shfl_xor((int)m19, 2));
    tau = m19;
    __syncthreads();
  }

  size_t base = ((size_t)(b * NN + i0 + pp)) * 80 + ss * KK;
#pragma unroll
  for (int s = 0; s < KK; ++s) cand[base + s] = (ushortT)(lst[s] & 2047u);
}

// ---------------------------------------------------------------- K1b: exact f64 rerank (p x4 unroll: 20 chains)
__launch_bounds__(256, 3)
__global__ void k_rerank(const float* __restrict__ x, const ushortT* __restrict__ cand,
                         int* __restrict__ idxout) {
  const int b  = blockIdx.y;
  const int i0 = blockIdx.x * 64;
  const int t  = threadIdx.x;
  const int grp = t >> 4, lg = t & 15;
  const int pp = t >> 2, ss = t & 3;

  __shared__ uint64 sK64[64][81];

  const float* xb = x + ((size_t)b * NN) * CC;

  for (int p = 0; p < 64; p += 4) {
    float4 vi[4]; size_t cb[4];
#pragma unroll
    for (int v = 0; v < 4; ++v) {
      vi[v] = ((const float4*)(xb + (size_t)(i0 + p + v) * CC))[lg];
      cb[v] = ((size_t)(b * NN + i0 + p + v)) * 80;
    }

    int jj[4][5];
#pragma unroll
    for (int u = 0; u < 5; ++u) {
      int q = grp + 16 * u;
#pragma unroll
      for (int v = 0; v < 4; ++v) jj[v][u] = (int)cand[cb[v] + q];
    }

    double dd[4][5];
#pragma unroll
    for (int u = 0; u < 5; ++u) {
#pragma unroll
      for (int v = 0; v < 4; ++v) {
        float4 vj = ((const float4*)(xb + (size_t)jj[v][u] * CC))[lg];
        double a0 = (double)vi[v].x - (double)vj.x;
        double a1 = (double)vi[v].y - (double)vj.y;
        double a2 = (double)vi[v].z - (double)vj.z;
        double a3 = (double)vi[v].w - (double)vj.w;
        dd[v][u] = a0 * a0 + a1 * a1 + a2 * a2 + a3 * a3;
      }
    }

#pragma unroll
    for (int off = 8; off > 0; off >>= 1) {
#pragma unroll
      for (int u = 0; u < 5; ++u)
#pragma unroll
        for (int v = 0; v < 4; ++v)
          dd[v][u] += __shfl_xor(dd[v][u], off, 16);
    }

    if (lg == 0) {
#pragma unroll
      for (int u = 0; u < 5; ++u) {
        int q = grp + 16 * u;
#pragma unroll
        for (int v = 0; v < 4; ++v) {
          uint64 bits = (uint64)__double_as_longlong(dd[v][u]);
          sK64[p + v][q] = (bits & ~2047ULL) | (uint64)jj[v][u];
        }
      }
    }
  }
  __syncthreads();

  if (ss == 0) {
    uint64 bl[KK];
#pragma unroll
    for (int s = 0; s < KK; ++s) bl[s] = ~0ULL;
    for (int q = 0; q < 80; ++q) {
      uint64 c = sK64[pp][q];
      if (c < bl[KK - 1]) {
        uint64 cur = c;
#pragma unroll
        for (int s = 0; s < KK; ++s) {
          uint64 lo = bl[s] < cur ? bl[s] : cur;
          cur = bl[s] < cur ? cur : bl[s];
          bl[s] = lo;
        }
      }
    }
    size_t base = ((size_t)(b * NN + i0 + pp)) * KK;
#pragma unroll
    for (int s = 0; s < KK; ++s) idxout[base + s] = (int)(bl[s] & 2047ULL);
  }
}

// ---------------------------------------------------------------- K2: edge MLP + max-agg
// 4 points/block, waves own one 16-col N-tile. Edge exact (xi + dH + dL);
// h1/h2 single bf16; agg via mapped-u32 atomicMax (no H3 buffer). LDS ~78KB
// -> 2 blocks/CU.
__launch_bounds__(256, 2)
__global__ void k_mlp(const float* __restrict__ x, const int* __restrict__ idx,
                      const float* __restrict__ w1, const float* __restrict__ b1,
                      const float* __restrict__ w2, const float* __restrict__ b2,
                      const float* __restrict__ w3, const float* __restrict__ b3,
                      float* __restrict__ agg) {
  const int b  = blockIdx.y;
  const int i0 = blockIdx.x * 4;
  const int t  = threadIdx.x;
  const int l  = t & 63, wv = t >> 6;
  const int la = l & 15, quad = l >> 4;

  __shared__ __align__(16) char sm[79936];
  ushortT (*sW1)[132] = (ushortT(*)[132])(sm + 0);       // 16896
  ushortT (*sW2)[68]  = (ushortT(*)[68])(sm + 16896);    // 8704
  ushortT (*sW3)[68]  = (ushortT(*)[68])(sm + 25600);    // 8704
  ushortT (*sXi)[68]  = (ushortT(*)[68])(sm + 34304);    // 10880 (layer2 out aliases)
  ushortT (*sDH)[68]  = (ushortT(*)[68])(sm + 45184);    // 10880
  ushortT (*sDL)[68]  = (ushortT(*)[68])(sm + 56064);    // 10880
  ushortT (*sH1)[68]  = (ushortT(*)[68])(sm + 66944);    // 10880
  uint32*  sAgg       = (uint32*)(sm + 77824);           // 1024
  float*   sB1        = (float*)(sm + 78848);
  float*   sB2        = (float*)(sm + 79104);
  float*   sB3        = (float*)(sm + 79360);
  int*     sJ         = (int*)(sm + 79616);              // 320 -> 79936

  for (int e = t; e < 8192; e += 256) {
    int k = e >> 6, n = e & 63;
    sW1[n][k] = f2bf(w1[e]);
  }
  for (int e = t; e < 4096; e += 256) {
    int k = e >> 6, n = e & 63;
    sW2[n][k] = f2bf(w2[e]);
    sW3[n][k] = f2bf(w3[e]);
  }
  if (t < 64) { sB1[t] = b1[t]; sB2[t] = b2[t]; sB3[t] = b3[t]; }
  if (t < 80) {
    int p = t / 20, kk = t - p * 20;
    int v = idx[((size_t)(b * NN + i0 + p)) * KK + kk];
    v = v < 0 ? 0 : (v > (NN - 1) ? (NN - 1) : v);
    sJ[t] = v;
  }
  sAgg[t] = 0u;
  __syncthreads();

  const float* xb = x + ((size_t)b * NN) * CC;
  for (int e = t; e < 1280; e += 256) {                  // 80 rows * 16 float4
    int r = e >> 4, c4g = e & 15, c4 = c4g * 4;
    int p = r / 20;
    float4 vi = ((const float4*)(xb + (size_t)(i0 + p) * CC))[c4g];
    float4 vj = ((const float4*)(xb + (size_t)sJ[r] * CC))[c4g];
    short4v hi, dh, dl;
    ushortT hh, ll;
    hi.x = (short)f2bf(vi.x); hi.y = (short)f2bf(vi.y);
    hi.z = (short)f2bf(vi.z); hi.w = (short)f2bf(vi.w);
    split2(vj.x - vi.x, hh, ll); dh.x = (short)hh; dl.x = (short)ll;
    split2(vj.y - vi.y, hh, ll); dh.y = (short)hh; dl.y = (short)ll;
    split2(vj.z - vi.z, hh, ll); dh.z = (short)hh; dl.z = (short)ll;
    split2(vj.w - vi.w, hh, ll); dh.w = (short)hh; dl.w = (short)ll;
    *(short4v*)&sXi[r][c4] = hi;
    *(short4v*)&sDH[r][c4] = dh;
    *(short4v*)&sDL[r][c4] = dl;
  }
  __syncthreads();

  const int c = wv * 16 + la;                            // this wave's output column

  // ---- layer 1: xi@W1a + dH@W1b + dL@W1b -> relu -> bf16 sH1
  {
    short8 bA[2], bB[2];
#pragma unroll
    for (int ks = 0; ks < 2; ++ks) {
      bA[ks] = ld8(&sW1[c][ks * 32 + quad * 8]);
      bB[ks] = ld8(&sW1[c][64 + ks * 32 + quad * 8]);
    }
#pragma unroll
    for (int m5 = 0; m5 < 5; ++m5) {
      floatx4 a = (floatx4){0.f, 0.f, 0.f, 0.f};
#pragma unroll
      for (int ks = 0; ks < 2; ++ks) {
        int kof = ks * 32 + quad * 8;
        short8 aXi = ld8(&sXi[m5 * 16 + la][kof]);
        short8 aDH = ld8(&sDH[m5 * 16 + la][kof]);
        short8 aDL = ld8(&sDL[m5 * 16 + la][kof]);
        a = __builtin_amdgcn_mfma_f32_16x16x32_bf16(aXi, bA[ks], a, 0, 0, 0);
        a = __builtin_amdgcn_mfma_f32_16x16x32_bf16(aDH, bB[ks], a, 0, 0, 0);
        a = __builtin_amdgcn_mfma_f32_16x16x32_bf16(aDL, bB[ks], a, 0, 0, 0);
      }
      float bia = sB1[c];
#pragma unroll
      for (int rg = 0; rg < 4; ++rg) {
        int r = m5 * 16 + quad * 4 + rg;
        sH1[r][c] = f2bf(fmaxf(a[rg] + bia, 0.f));
      }
    }
  }
  __syncthreads();

  // ---- layer 2: h1@W2 -> relu -> bf16 sH2 (aliases sXi)
  ushortT (*sH2)[68] = sXi;
  {
    short8 bf[2];
#pragma unroll
    for (int ks = 0; ks < 2; ++ks)
      bf[ks] = ld8(&sW2[c][ks * 32 + quad * 8]);
#pragma unroll
    for (int m5 = 0; m5 < 5; ++m5) {
      floatx4 a = (floatx4){0.f, 0.f, 0.f, 0.f};
#pragma unroll
      for (int ks = 0; ks < 2; ++ks) {
        short8 aH = ld8(&sH1[m5 * 16 + la][ks * 32 + quad * 8]);
        a = __builtin_amdgcn_mfma_f32_16x16x32_bf16(aH, bf[ks], a, 0, 0, 0);
      }
      float bia = sB2[c];
#pragma unroll
      for (int rg = 0; rg < 4; ++rg) {
        int r = m5 * 16 + quad * 4 + rg;
        sH2[r][c] = f2bf(fmaxf(a[rg] + bia, 0.f));
      }
    }
  }
  __syncthreads();

  // ---- layer 3: h2@W3 + b3 -> mapped-u32 atomicMax into sAgg
  {
    short8 bf[2];
#pragma unroll
    for (int ks = 0; ks < 2; ++ks)
      bf[ks] = ld8(&sW3[c][ks * 32 + quad * 8]);
#pragma unroll
    for (int m5 = 0; m5 < 5; ++m5) {
      floatx4 a = (floatx4){0.f, 0.f, 0.f, 0.f};
#pragma unroll
      for (int ks = 0; ks < 2; ++ks) {
        short8 aH = ld8(&sH2[m5 * 16 + la][ks * 32 + quad * 8]);
        a = __builtin_amdgcn_mfma_f32_16x16x32_bf16(aH, bf[ks], a, 0, 0, 0);
      }
      float bia = sB3[c];
#pragma unroll
      for (int rg = 0; rg < 4; ++rg) {
        int r = m5 * 16 + quad * 4 + rg;
        int p = r / 20;
        atomicMax(&sAgg[p * 64 + c], fmap(a[rg] + bia));
      }
    }
  }
  __syncthreads();

  {
    int p = t >> 6, cc = t & 63;
    agg[((size_t)(b * NN + i0 + p)) * CC + cc] = funmap(sAgg[t]);
  }
}

// ---------------------------------------------------------------- K3: SE (f32)
__global__ void k_se(const float* __restrict__ agg, const float* __restrict__ sew1,
                     const float* __restrict__ sew2, float* __restrict__ y) {
  int b = blockIdx.x, t = threadIdx.x;
  int c = t & 63, q = t >> 6;
  __shared__ float part[4][64];
  __shared__ float sv[64];
  __shared__ float hid[4];
  const float* ab = agg + ((size_t)b * NN) * CC;
  float s = 0.f;
  for (int n = q * 512; n < q * 512 + 512; ++n) s += ab[(size_t)n * CC + c];
  part[q][c] = s;
  __syncthreads();
  if (t < 64) sv[t] = (part[0][t] + part[1][t] + part[2][t] + part[3][t]) * (1.f / 2048.f);
  __syncthreads();
  if (t < 4) {
    float a = 0.f;
    for (int cc = 0; cc < 64; ++cc) a += sv[cc] * sew1[cc * 4 + t];
    hid[t] = fmaxf(a, 0.f);
  }
  __syncthreads();
  if (t < 64) {
    float a = 0.f;
#pragma unroll
    for (int h = 0; h < 4; ++h) a += hid[h] * sew2[h * 64 + t];
    y[b * 64 + t] = 1.f / (1.f + expf(-a));
  }
}

// ---------------------------------------------------------------- K4: per-point stats (f32)
__global__ void k_stats(const float* __restrict__ agg, const float* __restrict__ y,
                        float* __restrict__ ycat) {
  int t = threadIdx.x;
  int gid = blockIdx.x * 4 + (t >> 6);
  int l = t & 63;
  int b = gid >> 11, i = gid & 2047;
  float v = agg[(size_t)gid * CC + l] * y[b * 64 + l];
  float s = v, mx = v;
#pragma unroll
  for (int off = 32; off > 0; off >>= 1) {
    s += __shfl_xor(s, off);
    mx = fmaxf(mx, __shfl_xor(mx, off));
  }
  if (l == 0) {
    ycat[b * 2 * NN + i] = s * (1.f / 64.f);
    ycat[b * 2 * NN + NN + i] = mx;
  }
}

// ---------------------------------------------------------------- K5: conv7 att + add (f32 out)
__global__ void k_final(const float* __restrict__ agg, const float* __restrict__ y,
                        const float* __restrict__ ycat, const float* __restrict__ saw,
                        const float* __restrict__ x, float* __restrict__ out) {
  int e = blockIdx.x * 256 + threadIdx.x;
  int ifl = e >> 6, c = e & 63;
  int b = ifl >> 11, i = ifl & 2047;
  float a = 0.f;
#pragma unroll
  for (int w = 0; w < 7; ++w) {
    int ii = i + w - 3;
    if (ii >= 0 && ii < NN) {
      a += ycat[b * 2 * NN + ii] * saw[w];
      a += ycat[b * 2 * NN + NN + ii] * saw[7 + w];
    }
  }
  float att = 1.f / (1.f + expf(-a));
  out[e] = agg[(size_t)ifl * CC + c] * y[b * 64 + c] * att + x[(size_t)e];
}

// ----------------------------------------------------------------
extern "C" void kernel_launch(void* const* d_in, const int* in_sizes, int n_in,
                              void* d_out, int out_size, void* d_ws, size_t ws_size,
                              hipStream_t stream) {
  const float* x    = (const float*)d_in[0];
  const float* w1   = (const float*)d_in[3];
  const float* b1   = (const float*)d_in[4];
  const float* w2   = (const float*)d_in[5];
  const float* b2   = (const float*)d_in[6];
  const float* w3   = (const float*)d_in[7];
  const float* b3   = (const float*)d_in[8];
  const float* sew1 = (const float*)d_in[9];
  const float* sew2 = (const float*)d_in[10];
  const float* saw  = (const float*)d_in[11];
  float* out = (float*)d_out;

  char* ws = (char*)d_ws;
  float*   sq   = (float*)  (ws);                          // 131072 B
  int*     idx  = (int*)    (ws + 131072);                 // 2621440 B
  ushortT* cand = (ushortT*)(ws + 2752512);                // 5242880 B (32768*80 u16)
  float*   agg  = (float*)  (ws + 2752512);                // 8388608 B (aliases cand; cand
                                                           // consumed before k_mlp writes)
  float*   y    = (float*)  (ws + 11141120);               // 4096 B
  float*   ycat = (float*)  (ws + 11145216);               // 262144 B -> total 11407360 B

  k_sq    <<<128,            256, 0, stream>>>(x, sq);
  k_knn   <<<dim3(32, 16),   256, 0, stream>>>(x, sq, cand);
  k_rerank<<<dim3(32, 16),   256, 0, stream>>>(x, cand, idx);
  k_mlp   <<<dim3(512, 16),  256, 0, stream>>>(x, idx, w1, b1, w2, b2, w3, b3, agg);
  k_se    <<<16,             256, 0, stream>>>(agg, sew1, sew2, y);
  k_stats <<<8192,           256, 0, stream>>>(agg, y, ycat);
  k_final <<<8192,           256, 0, stream>>>(agg, y, ycat, saw, x, out);
}

// Round 12
// 536.719 us; speedup vs baseline: 1.5025x; 1.0644x over previous
//
#include <hip/hip_runtime.h>

typedef unsigned int uint32;
typedef unsigned long long uint64;
typedef unsigned short ushortT;
typedef __attribute__((ext_vector_type(8))) short short8;
typedef __attribute__((ext_vector_type(4))) short short4v;
typedef __attribute__((ext_vector_type(4))) float floatx4;

#define DEV static __device__ __forceinline__

#define NN 2048
#define CC 64
#define KK 20

DEV float bf2f(ushortT h) {
  union { uint32 u; float f; } c; c.u = ((uint32)h) << 16; return c.f;
}
DEV ushortT f2bf(float f) {
  union { float f; uint32 u; } c; c.f = f;
  uint32 r = c.u + 0x7FFFu + ((c.u >> 16) & 1u);   // RNE
  return (ushortT)(r >> 16);
}
DEV void split2(float v, ushortT& h, ushortT& l) {
  h = f2bf(v);
  l = f2bf(v - bf2f(h));
}
DEV uint32 fmap(float f) {            // monotone f32 -> u32
  uint32 u = __float_as_uint(f);
  return (u & 0x80000000u) ? ~u : (u | 0x80000000u);
}
DEV float funmap(uint32 m) {
  uint32 u = (m & 0x80000000u) ? (m ^ 0x80000000u) : ~m;
  return __uint_as_float(u);
}
DEV short8 ld8(const ushortT* p) {    // 8B-aligned 16B load as two b64
  short4v a = *(const short4v*)p;
  short4v b = *(const short4v*)(p + 4);
  short8 r;
  r[0] = a.x; r[1] = a.y; r[2] = a.z; r[3] = a.w;
  r[4] = b.x; r[5] = b.y; r[6] = b.z; r[7] = b.w;
  return r;
}

// ---------------------------------------------------------------- K0: sq norms (f32)
__global__ void k_sq(const float* __restrict__ x, float* __restrict__ sq) {
  int p = blockIdx.x * 256 + threadIdx.x;
  const float4* row = (const float4*)(x + (size_t)p * CC);
  float s = 0.f;
#pragma unroll
  for (int q = 0; q < 16; ++q) {
    float4 v = row[q];
    s += v.x * v.x + v.y * v.y + v.z * v.z + v.w * v.w;
  }
  sq[p] = s;
}

// ---------------------------------------------------------------- K1: KNN stage 1 (unchanged)
__launch_bounds__(256, 3)
__global__ void k_knn(const float* __restrict__ x, const float* __restrict__ sq,
                      ushortT* __restrict__ cand) {
  const int b  = blockIdx.y;
  const int i0 = blockIdx.x * 64;
  const int t  = threadIdx.x;
  const int l  = t & 63, wv = t >> 6;
  const int la = l & 15, quad = l >> 4;
  const int pp = t >> 2, ss = t & 3;

  __shared__ __align__(16) char sm[52992];
  ushortT (*sXj)[72]  = (ushortT(*)[72])(sm);
  uint32  (*sKey)[132]= (uint32(*)[132])(sm + 18432);
  float*   sSqi       = (float*)(sm + 52224);
  float*   sSqj       = (float*)(sm + 52480);

  const float* xb = x + ((size_t)b * NN) * CC;

  const int mt0 = (wv & 1) * 2;
  const int nt0 = (wv >> 1) * 4;

  short8 afrag[2][2];
#pragma unroll
  for (int m = 0; m < 2; ++m) {
    const float* rowp = xb + (size_t)(i0 + (mt0 + m) * 16 + la) * CC;
#pragma unroll
    for (int ks = 0; ks < 2; ++ks) {
      int kof = ks * 32 + quad * 8;
      float4 v0 = *(const float4*)(rowp + kof);
      float4 v1 = *(const float4*)(rowp + kof + 4);
      short8 f;
      f[0] = (short)f2bf(v0.x); f[1] = (short)f2bf(v0.y);
      f[2] = (short)f2bf(v0.z); f[3] = (short)f2bf(v0.w);
      f[4] = (short)f2bf(v1.x); f[5] = (short)f2bf(v1.y);
      f[6] = (short)f2bf(v1.z); f[7] = (short)f2bf(v1.w);
      afrag[m][ks] = f;
    }
  }
  if (t < 64) sSqi[t] = sq[b * NN + i0 + t];

  for (int e = t; e < 2048; e += 256) {
    int r = e >> 4, c4 = (e & 15) * 4;
    float4 v = ((const float4*)(xb + (size_t)r * CC))[e & 15];
    short4v h;
    h.x = (short)f2bf(v.x); h.y = (short)f2bf(v.y);
    h.z = (short)f2bf(v.z); h.w = (short)f2bf(v.w);
    *(short4v*)&sXj[r][c4] = h;
  }
  if (t < 128) sSqj[t] = sq[b * NN + t];

  uint32 lst[KK];
#pragma unroll
  for (int s = 0; s < KK; ++s) lst[s] = 0xFFFFFFFFu;
  uint32 tau = 0xFFFFFFFFu;

  __syncthreads();

  for (int jt = 0; jt < 16; ++jt) {
    const int j0 = jt * 128;

    floatx4 acc[2][4];
#pragma unroll
    for (int m = 0; m < 2; ++m)
#pragma unroll
      for (int n = 0; n < 4; ++n) acc[m][n] = (floatx4){0.f, 0.f, 0.f, 0.f};

#pragma unroll
    for (int ks = 0; ks < 2; ++ks) {
      int kof = ks * 32 + quad * 8;
#pragma unroll
      for (int n = 0; n < 4; ++n) {
        short8 bv = *(const short8*)&sXj[(nt0 + n) * 16 + la][kof];
        acc[0][n] = __builtin_amdgcn_mfma_f32_16x16x32_bf16(afrag[0][ks], bv, acc[0][n], 0, 0, 0);
        acc[1][n] = __builtin_amdgcn_mfma_f32_16x16x32_bf16(afrag[1][ks], bv, acc[1][n], 0, 0, 0);
      }
    }

#pragma unroll
    for (int m = 0; m < 2; ++m) {
#pragma unroll
      for (int n = 0; n < 4; ++n) {
        int jl = (nt0 + n) * 16 + la;
        float dj = sSqj[jl];
        uint32 jg = (uint32)(j0 + jl);
#pragma unroll
        for (int rg = 0; rg < 4; ++rg) {
          int il = (mt0 + m) * 16 + quad * 4 + rg;
          float d = fmaxf(sSqi[il] + dj - 2.0f * acc[m][n][rg], 0.f);
          sKey[il][jl] = (__float_as_uint(d) & 0xFFFFF800u) | jg;
        }
      }
    }
    __syncthreads();

#pragma unroll
    for (int k = 0; k < 32; ++k) {
      uint32 c = sKey[pp][ss + 4 * k];
      if (c < tau) {
        uint32 cur = c;
#pragma unroll
        for (int s = 0; s < KK; ++s) {
          uint32 lo = min(lst[s], cur);
          cur = max(lst[s], cur);
          lst[s] = lo;
        }
      }
    }

    if (jt < 15) {
      const int jn = (jt + 1) * 128;
      for (int e = t; e < 2048; e += 256) {
        int r = e >> 4, c4 = (e & 15) * 4;
        float4 v = ((const float4*)(xb + (size_t)(jn + r) * CC))[e & 15];
        short4v h;
        h.x = (short)f2bf(v.x); h.y = (short)f2bf(v.y);
        h.z = (short)f2bf(v.z); h.w = (short)f2bf(v.w);
        *(short4v*)&sXj[r][c4] = h;
      }
      if (t < 128) sSqj[t] = sq[b * NN + jn + t];
    }

    uint32 m19 = lst[KK - 1];
    m19 = min(m19, (uint32)__shfl_xor((int)m19, 1));
    m19 = min(m19, (uint32)__shfl_xor((int)m19, 2));
    tau = m19;
    __syncthreads();
  }

  size_t base = ((size_t)(b * NN + i0 + pp)) * 80 + ss * KK;
#pragma unroll
  for (int s = 0; s < KK; ++s) cand[base + s] = (ushortT)(lst[s] & 2047u);
}

// ---------------------------------------------------------------- K1b: exact f64 rerank
// 16 points/block (grid 2048x16 -> up to 8 blocks/CU). One 16-lane group per
// point; 80 candidates in q-batches of 8 independent chains. LDS 10.4 KB.
__launch_bounds__(256, 4)
__global__ void k_rerank(const float* __restrict__ x, const ushortT* __restrict__ cand,
                         int* __restrict__ idxout) {
  const int b  = blockIdx.y;
  const int i0 = blockIdx.x * 16;
  const int t  = threadIdx.x;
  const int grp = t >> 4, lg = t & 15;

  __shared__ uint64 sK64[16][81];

  const float* xb = x + ((size_t)b * NN) * CC;
  const int p = i0 + grp;
  float4 vi = ((const float4*)(xb + (size_t)p * CC))[lg];
  size_t cb = ((size_t)(b * NN + p)) * 80;

#pragma unroll
  for (int q0 = 0; q0 < 80; q0 += 8) {
    int jj[8];
#pragma unroll
    for (int u = 0; u < 8; ++u) jj[u] = (int)cand[cb + q0 + u];

    double dd[8];
#pragma unroll
    for (int u = 0; u < 8; ++u) {
      float4 vj = ((const float4*)(xb + (size_t)jj[u] * CC))[lg];
      double a0 = (double)vi.x - (double)vj.x;
      double a1 = (double)vi.y - (double)vj.y;
      double a2 = (double)vi.z - (double)vj.z;
      double a3 = (double)vi.w - (double)vj.w;
      dd[u] = a0 * a0 + a1 * a1 + a2 * a2 + a3 * a3;
    }

#pragma unroll
    for (int off = 8; off > 0; off >>= 1)
#pragma unroll
      for (int u = 0; u < 8; ++u)
        dd[u] += __shfl_xor(dd[u], off, 16);

    if (lg == 0) {
#pragma unroll
      for (int u = 0; u < 8; ++u) {
        uint64 bits = (uint64)__double_as_longlong(dd[u]);   // d >= 0: order-preserving
        sK64[grp][q0 + u] = (bits & ~2047ULL) | (uint64)jj[u];
      }
    }
  }
  __syncthreads();

  if (t < 16) {
    uint64 bl[KK];
#pragma unroll
    for (int s = 0; s < KK; ++s) bl[s] = ~0ULL;
    for (int q = 0; q < 80; ++q) {
      uint64 c = sK64[t][q];
      if (c < bl[KK - 1]) {
        uint64 cur = c;
#pragma unroll
        for (int s = 0; s < KK; ++s) {
          uint64 lo = bl[s] < cur ? bl[s] : cur;
          cur = bl[s] < cur ? cur : bl[s];
          bl[s] = lo;
        }
      }
    }
    size_t base = ((size_t)(b * NN + i0 + t)) * KK;
#pragma unroll
    for (int s = 0; s < KK; ++s) idxout[base + s] = (int)(bl[s] & 2047ULL);
  }
}

// ---------------------------------------------------------------- K2: edge MLP + max-agg (unchanged)
__launch_bounds__(256, 2)
__global__ void k_mlp(const float* __restrict__ x, const int* __restrict__ idx,
                      const float* __restrict__ w1, const float* __restrict__ b1,
                      const float* __restrict__ w2, const float* __restrict__ b2,
                      const float* __restrict__ w3, const float* __restrict__ b3,
                      float* __restrict__ agg) {
  const int b  = blockIdx.y;
  const int i0 = blockIdx.x * 4;
  const int t  = threadIdx.x;
  const int l  = t & 63, wv = t >> 6;
  const int la = l & 15, quad = l >> 4;

  __shared__ __align__(16) char sm[79936];
  ushortT (*sW1)[132] = (ushortT(*)[132])(sm + 0);
  ushortT (*sW2)[68]  = (ushortT(*)[68])(sm + 16896);
  ushortT (*sW3)[68]  = (ushortT(*)[68])(sm + 25600);
  ushortT (*sXi)[68]  = (ushortT(*)[68])(sm + 34304);
  ushortT (*sDH)[68]  = (ushortT(*)[68])(sm + 45184);
  ushortT (*sDL)[68]  = (ushortT(*)[68])(sm + 56064);
  ushortT (*sH1)[68]  = (ushortT(*)[68])(sm + 66944);
  uint32*  sAgg       = (uint32*)(sm + 77824);
  float*   sB1        = (float*)(sm + 78848);
  float*   sB2        = (float*)(sm + 79104);
  float*   sB3        = (float*)(sm + 79360);
  int*     sJ         = (int*)(sm + 79616);

  for (int e = t; e < 8192; e += 256) {
    int k = e >> 6, n = e & 63;
    sW1[n][k] = f2bf(w1[e]);
  }
  for (int e = t; e < 4096; e += 256) {
    int k = e >> 6, n = e & 63;
    sW2[n][k] = f2bf(w2[e]);
    sW3[n][k] = f2bf(w3[e]);
  }
  if (t < 64) { sB1[t] = b1[t]; sB2[t] = b2[t]; sB3[t] = b3[t]; }
  if (t < 80) {
    int p = t / 20, kk = t - p * 20;
    int v = idx[((size_t)(b * NN + i0 + p)) * KK + kk];
    v = v < 0 ? 0 : (v > (NN - 1) ? (NN - 1) : v);
    sJ[t] = v;
  }
  sAgg[t] = 0u;
  __syncthreads();

  const float* xb = x + ((size_t)b * NN) * CC;
  for (int e = t; e < 1280; e += 256) {
    int r = e >> 4, c4g = e & 15, c4 = c4g * 4;
    int p = r / 20;
    float4 vi = ((const float4*)(xb + (size_t)(i0 + p) * CC))[c4g];
    float4 vj = ((const float4*)(xb + (size_t)sJ[r] * CC))[c4g];
    short4v hi, dh, dl;
    ushortT hh, ll;
    hi.x = (short)f2bf(vi.x); hi.y = (short)f2bf(vi.y);
    hi.z = (short)f2bf(vi.z); hi.w = (short)f2bf(vi.w);
    split2(vj.x - vi.x, hh, ll); dh.x = (short)hh; dl.x = (short)ll;
    split2(vj.y - vi.y, hh, ll); dh.y = (short)hh; dl.y = (short)ll;
    split2(vj.z - vi.z, hh, ll); dh.z = (short)hh; dl.z = (short)ll;
    split2(vj.w - vi.w, hh, ll); dh.w = (short)hh; dl.w = (short)ll;
    *(short4v*)&sXi[r][c4] = hi;
    *(short4v*)&sDH[r][c4] = dh;
    *(short4v*)&sDL[r][c4] = dl;
  }
  __syncthreads();

  const int c = wv * 16 + la;

  // ---- layer 1
  {
    short8 bA[2], bB[2];
#pragma unroll
    for (int ks = 0; ks < 2; ++ks) {
      bA[ks] = ld8(&sW1[c][ks * 32 + quad * 8]);
      bB[ks] = ld8(&sW1[c][64 + ks * 32 + quad * 8]);
    }
#pragma unroll
    for (int m5 = 0; m5 < 5; ++m5) {
      floatx4 a = (floatx4){0.f, 0.f, 0.f, 0.f};
#pragma unroll
      for (int ks = 0; ks < 2; ++ks) {
        int kof = ks * 32 + quad * 8;
        short8 aXi = ld8(&sXi[m5 * 16 + la][kof]);
        short8 aDH = ld8(&sDH[m5 * 16 + la][kof]);
        short8 aDL = ld8(&sDL[m5 * 16 + la][kof]);
        a = __builtin_amdgcn_mfma_f32_16x16x32_bf16(aXi, bA[ks], a, 0, 0, 0);
        a = __builtin_amdgcn_mfma_f32_16x16x32_bf16(aDH, bB[ks], a, 0, 0, 0);
        a = __builtin_amdgcn_mfma_f32_16x16x32_bf16(aDL, bB[ks], a, 0, 0, 0);
      }
      float bia = sB1[c];
#pragma unroll
      for (int rg = 0; rg < 4; ++rg) {
        int r = m5 * 16 + quad * 4 + rg;
        sH1[r][c] = f2bf(fmaxf(a[rg] + bia, 0.f));
      }
    }
  }
  __syncthreads();

  // ---- layer 2
  ushortT (*sH2)[68] = sXi;
  {
    short8 bf[2];
#pragma unroll
    for (int ks = 0; ks < 2; ++ks)
      bf[ks] = ld8(&sW2[c][ks * 32 + quad * 8]);
#pragma unroll
    for (int m5 = 0; m5 < 5; ++m5) {
      floatx4 a = (floatx4){0.f, 0.f, 0.f, 0.f};
#pragma unroll
      for (int ks = 0; ks < 2; ++ks) {
        short8 aH = ld8(&sH1[m5 * 16 + la][ks * 32 + quad * 8]);
        a = __builtin_amdgcn_mfma_f32_16x16x32_bf16(aH, bf[ks], a, 0, 0, 0);
      }
      float bia = sB2[c];
#pragma unroll
      for (int rg = 0; rg < 4; ++rg) {
        int r = m5 * 16 + quad * 4 + rg;
        sH2[r][c] = f2bf(fmaxf(a[rg] + bia, 0.f));
      }
    }
  }
  __syncthreads();

  // ---- layer 3
  {
    short8 bf[2];
#pragma unroll
    for (int ks = 0; ks < 2; ++ks)
      bf[ks] = ld8(&sW3[c][ks * 32 + quad * 8]);
#pragma unroll
    for (int m5 = 0; m5 < 5; ++m5) {
      floatx4 a = (floatx4){0.f, 0.f, 0.f, 0.f};
#pragma unroll
      for (int ks = 0; ks < 2; ++ks) {
        short8 aH = ld8(&sH2[m5 * 16 + la][ks * 32 + quad * 8]);
        a = __builtin_amdgcn_mfma_f32_16x16x32_bf16(aH, bf[ks], a, 0, 0, 0);
      }
      float bia = sB3[c];
#pragma unroll
      for (int rg = 0; rg < 4; ++rg) {
        int r = m5 * 16 + quad * 4 + rg;
        int p = r / 20;
        atomicMax(&sAgg[p * 64 + c], fmap(a[rg] + bia));
      }
    }
  }
  __syncthreads();

  {
    int p = t >> 6, cc = t & 63;
    agg[((size_t)(b * NN + i0 + p)) * CC + cc] = funmap(sAgg[t]);
  }
}

// ---------------------------------------------------------------- K3: SE (f32)
__global__ void k_se(const float* __restrict__ agg, const float* __restrict__ sew1,
                     const float* __restrict__ sew2, float* __restrict__ y) {
  int b = blockIdx.x, t = threadIdx.x;
  int c = t & 63, q = t >> 6;
  __shared__ float part[4][64];
  __shared__ float sv[64];
  __shared__ float hid[4];
  const float* ab = agg + ((size_t)b * NN) * CC;
  float s = 0.f;
  for (int n = q * 512; n < q * 512 + 512; ++n) s += ab[(size_t)n * CC + c];
  part[q][c] = s;
  __syncthreads();
  if (t < 64) sv[t] = (part[0][t] + part[1][t] + part[2][t] + part[3][t]) * (1.f / 2048.f);
  __syncthreads();
  if (t < 4) {
    float a = 0.f;
    for (int cc = 0; cc < 64; ++cc) a += sv[cc] * sew1[cc * 4 + t];
    hid[t] = fmaxf(a, 0.f);
  }
  __syncthreads();
  if (t < 64) {
    float a = 0.f;
#pragma unroll
    for (int h = 0; h < 4; ++h) a += hid[h] * sew2[h * 64 + t];
    y[b * 64 + t] = 1.f / (1.f + expf(-a));
  }
}

// ---------------------------------------------------------------- K4: per-point stats (f32)
__global__ void k_stats(const float* __restrict__ agg, const float* __restrict__ y,
                        float* __restrict__ ycat) {
  int t = threadIdx.x;
  int gid = blockIdx.x * 4 + (t >> 6);
  int l = t & 63;
  int b = gid >> 11, i = gid & 2047;
  float v = agg[(size_t)gid * CC + l] * y[b * 64 + l];
  float s = v, mx = v;
#pragma unroll
  for (int off = 32; off > 0; off >>= 1) {
    s += __shfl_xor(s, off);
    mx = fmaxf(mx, __shfl_xor(mx, off));
  }
  if (l == 0) {
    ycat[b * 2 * NN + i] = s * (1.f / 64.f);
    ycat[b * 2 * NN + NN + i] = mx;
  }
}

// ---------------------------------------------------------------- K5: conv7 att + add (f32 out)
__global__ void k_final(const float* __restrict__ agg, const float* __restrict__ y,
                        const float* __restrict__ ycat, const float* __restrict__ saw,
                        const float* __restrict__ x, float* __restrict__ out) {
  int e = blockIdx.x * 256 + threadIdx.x;
  int ifl = e >> 6, c = e & 63;
  int b = ifl >> 11, i = ifl & 2047;
  float a = 0.f;
#pragma unroll
  for (int w = 0; w < 7; ++w) {
    int ii = i + w - 3;
    if (ii >= 0 && ii < NN) {
      a += ycat[b * 2 * NN + ii] * saw[w];
      a += ycat[b * 2 * NN + NN + ii] * saw[7 + w];
    }
  }
  float att = 1.f / (1.f + expf(-a));
  out[e] = agg[(size_t)ifl * CC + c] * y[b * 64 + c] * att + x[(size_t)e];
}

// ----------------------------------------------------------------
extern "C" void kernel_launch(void* const* d_in, const int* in_sizes, int n_in,
                              void* d_out, int out_size, void* d_ws, size_t ws_size,
                              hipStream_t stream) {
  const float* x    = (const float*)d_in[0];
  const float* w1   = (const float*)d_in[3];
  const float* b1   = (const float*)d_in[4];
  const float* w2   = (const float*)d_in[5];
  const float* b2   = (const float*)d_in[6];
  const float* w3   = (const float*)d_in[7];
  const float* b3   = (const float*)d_in[8];
  const float* sew1 = (const float*)d_in[9];
  const float* sew2 = (const float*)d_in[10];
  const float* saw  = (const float*)d_in[11];
  float* out = (float*)d_out;

  char* ws = (char*)d_ws;
  float*   sq   = (float*)  (ws);                          // 131072 B
  int*     idx  = (int*)    (ws + 131072);                 // 2621440 B
  ushortT* cand = (ushortT*)(ws + 2752512);                // 5242880 B (32768*80 u16)
  float*   agg  = (float*)  (ws + 2752512);                // 8388608 B (aliases cand; cand
                                                           // consumed before k_mlp writes)
  float*   y    = (float*)  (ws + 11141120);               // 4096 B
  float*   ycat = (float*)  (ws + 11145216);               // 262144 B -> total 11407360 B

  k_sq    <<<128,            256, 0, stream>>>(x, sq);
  k_knn   <<<dim3(32, 16),   256, 0, stream>>>(x, sq, cand);
  k_rerank<<<dim3(128, 16),  256, 0, stream>>>(x, cand, idx);
  k_mlp   <<<dim3(512, 16),  256, 0, stream>>>(x, idx, w1, b1, w2, b2, w3, b3, agg);
  k_se    <<<16,             256, 0, stream>>>(agg, sew1, sew2, y);
  k_stats <<<8192,           256, 0, stream>>>(agg, y, ycat);
  k_final <<<8192,           256, 0, stream>>>(agg, y, ycat, saw, x, out);
}

// Round 13
// 514.042 us; speedup vs baseline: 1.5688x; 1.0441x over previous
//
#include <hip/hip_runtime.h>

typedef unsigned int uint32;
typedef unsigned long long uint64;
typedef unsigned short ushortT;
typedef __attribute__((ext_vector_type(8))) short short8;
typedef __attribute__((ext_vector_type(4))) short short4v;
typedef __attribute__((ext_vector_type(4))) float floatx4;

#define DEV static __device__ __forceinline__

#define NN 2048
#define CC 64
#define KK 20

DEV float bf2f(ushortT h) {
  union { uint32 u; float f; } c; c.u = ((uint32)h) << 16; return c.f;
}
DEV ushortT f2bf(float f) {
  union { float f; uint32 u; } c; c.f = f;
  uint32 r = c.u + 0x7FFFu + ((c.u >> 16) & 1u);   // RNE
  return (ushortT)(r >> 16);
}
DEV void split2(float v, ushortT& h, ushortT& l) {
  h = f2bf(v);
  l = f2bf(v - bf2f(h));
}
DEV uint32 fmap(float f) {            // monotone f32 -> u32
  uint32 u = __float_as_uint(f);
  return (u & 0x80000000u) ? ~u : (u | 0x80000000u);
}
DEV float funmap(uint32 m) {
  uint32 u = (m & 0x80000000u) ? (m ^ 0x80000000u) : ~m;
  return __uint_as_float(u);
}
DEV short8 ld8(const ushortT* p) {    // 8B-aligned 16B load as two b64
  short4v a = *(const short4v*)p;
  short4v b = *(const short4v*)(p + 4);
  short8 r;
  r[0] = a.x; r[1] = a.y; r[2] = a.z; r[3] = a.w;
  r[4] = b.x; r[5] = b.y; r[6] = b.z; r[7] = b.w;
  return r;
}

// ---------------------------------------------------------------- K0: sq norms + bf16 image of x
__global__ void k_sq(const float* __restrict__ x, float* __restrict__ sq,
                     ushortT* __restrict__ xbf) {
  int p = blockIdx.x * 256 + threadIdx.x;
  const float4* row = (const float4*)(x + (size_t)p * CC);
  ushortT* orow = xbf + (size_t)p * CC;
  float s = 0.f;
#pragma unroll
  for (int q = 0; q < 16; ++q) {
    float4 v = row[q];
    s += v.x * v.x + v.y * v.y + v.z * v.z + v.w * v.w;
    short4v h;
    h.x = (short)f2bf(v.x); h.y = (short)f2bf(v.y);
    h.z = (short)f2bf(v.z); h.w = (short)f2bf(v.w);
    *(short4v*)(orow + q * 4) = h;
  }
  sq[p] = s;
}

// ---------------------------------------------------------------- K1: KNN stage 1
// Stages pre-converted bf16 tiles (pure copies, no f2bf); dense key tile +
// tau-filtered register top-20 per owner thread (4/point); 80 cands out.
__launch_bounds__(256, 3)
__global__ void k_knn(const ushortT* __restrict__ xbf, const float* __restrict__ sq,
                      ushortT* __restrict__ cand) {
  const int b  = blockIdx.y;
  const int i0 = blockIdx.x * 64;
  const int t  = threadIdx.x;
  const int l  = t & 63, wv = t >> 6;
  const int la = l & 15, quad = l >> 4;
  const int pp = t >> 2, ss = t & 3;

  __shared__ __align__(16) char sm[52992];
  ushortT (*sXj)[72]  = (ushortT(*)[72])(sm);
  uint32  (*sKey)[132]= (uint32(*)[132])(sm + 18432);
  float*   sSqi       = (float*)(sm + 52224);
  float*   sSqj       = (float*)(sm + 52480);

  const ushortT* xbb = xbf + ((size_t)b * NN) * CC;

  const int mt0 = (wv & 1) * 2;
  const int nt0 = (wv >> 1) * 4;

  // A-fragments: direct bf16 16B loads
  short8 afrag[2][2];
#pragma unroll
  for (int m = 0; m < 2; ++m) {
    const ushortT* rowp = xbb + (size_t)(i0 + (mt0 + m) * 16 + la) * CC;
#pragma unroll
    for (int ks = 0; ks < 2; ++ks)
      afrag[m][ks] = *(const short8*)(rowp + ks * 32 + quad * 8);
  }
  if (t < 64) sSqi[t] = sq[b * NN + i0 + t];

  // stage tile 0: pure copy (2 threads/row, 32 shorts each)
  {
    int r = t >> 1, co = (t & 1) * 32;
    const ushortT* src = xbb + (size_t)r * CC + co;
#pragma unroll
    for (int i = 0; i < 4; ++i)
      *(uint4*)&sXj[r][co + i * 8] = *(const uint4*)(src + i * 8);
  }
  if (t < 128) sSqj[t] = sq[b * NN + t];

  uint32 lst[KK];
#pragma unroll
  for (int s = 0; s < KK; ++s) lst[s] = 0xFFFFFFFFu;
  uint32 tau = 0xFFFFFFFFu;

  __syncthreads();

  for (int jt = 0; jt < 16; ++jt) {
    const int j0 = jt * 128;

    floatx4 acc[2][4];
#pragma unroll
    for (int m = 0; m < 2; ++m)
#pragma unroll
      for (int n = 0; n < 4; ++n) acc[m][n] = (floatx4){0.f, 0.f, 0.f, 0.f};

#pragma unroll
    for (int ks = 0; ks < 2; ++ks) {
      int kof = ks * 32 + quad * 8;
#pragma unroll
      for (int n = 0; n < 4; ++n) {
        short8 bv = *(const short8*)&sXj[(nt0 + n) * 16 + la][kof];
        acc[0][n] = __builtin_amdgcn_mfma_f32_16x16x32_bf16(afrag[0][ks], bv, acc[0][n], 0, 0, 0);
        acc[1][n] = __builtin_amdgcn_mfma_f32_16x16x32_bf16(afrag[1][ks], bv, acc[1][n], 0, 0, 0);
      }
    }

#pragma unroll
    for (int m = 0; m < 2; ++m) {
#pragma unroll
      for (int n = 0; n < 4; ++n) {
        int jl = (nt0 + n) * 16 + la;
        float dj = sSqj[jl];
        uint32 jg = (uint32)(j0 + jl);
#pragma unroll
        for (int rg = 0; rg < 4; ++rg) {
          int il = (mt0 + m) * 16 + quad * 4 + rg;
          float d = fmaxf(sSqi[il] + dj - 2.0f * acc[m][n][rg], 0.f);
          sKey[il][jl] = (__float_as_uint(d) & 0xFFFFF800u) | jg;
        }
      }
    }
    __syncthreads();

#pragma unroll
    for (int k = 0; k < 32; ++k) {
      uint32 c = sKey[pp][ss + 4 * k];
      if (c < tau) {
        uint32 cur = c;
#pragma unroll
        for (int s = 0; s < KK; ++s) {
          uint32 lo = min(lst[s], cur);
          cur = max(lst[s], cur);
          lst[s] = lo;
        }
      }
    }

    if (jt < 15) {
      const int jn = (jt + 1) * 128;
      int r = t >> 1, co = (t & 1) * 32;
      const ushortT* src = xbb + (size_t)(jn + r) * CC + co;
#pragma unroll
      for (int i = 0; i < 4; ++i)
        *(uint4*)&sXj[r][co + i * 8] = *(const uint4*)(src + i * 8);
      if (t < 128) sSqj[t] = sq[b * NN + jn + t];
    }

    uint32 m19 = lst[KK - 1];
    m19 = min(m19, (uint32)__shfl_xor((int)m19, 1));
    m19 = min(m19, (uint32)__shfl_xor((int)m19, 2));
    tau = m19;
    __syncthreads();
  }

  size_t base = ((size_t)(b * NN + i0 + pp)) * 80 + ss * KK;
#pragma unroll
  for (int s = 0; s < KK; ++s) cand[base + s] = (ushortT)(lst[s] & 2047u);
}

// ---------------------------------------------------------------- K1b: exact f64 rerank (unchanged)
__launch_bounds__(256, 4)
__global__ void k_rerank(const float* __restrict__ x, const ushortT* __restrict__ cand,
                         int* __restrict__ idxout) {
  const int b  = blockIdx.y;
  const int i0 = blockIdx.x * 16;
  const int t  = threadIdx.x;
  const int grp = t >> 4, lg = t & 15;

  __shared__ uint64 sK64[16][81];

  const float* xb = x + ((size_t)b * NN) * CC;
  const int p = i0 + grp;
  float4 vi = ((const float4*)(xb + (size_t)p * CC))[lg];
  size_t cb = ((size_t)(b * NN + p)) * 80;

#pragma unroll
  for (int q0 = 0; q0 < 80; q0 += 8) {
    int jj[8];
#pragma unroll
    for (int u = 0; u < 8; ++u) jj[u] = (int)cand[cb + q0 + u];

    double dd[8];
#pragma unroll
    for (int u = 0; u < 8; ++u) {
      float4 vj = ((const float4*)(xb + (size_t)jj[u] * CC))[lg];
      double a0 = (double)vi.x - (double)vj.x;
      double a1 = (double)vi.y - (double)vj.y;
      double a2 = (double)vi.z - (double)vj.z;
      double a3 = (double)vi.w - (double)vj.w;
      dd[u] = a0 * a0 + a1 * a1 + a2 * a2 + a3 * a3;
    }

#pragma unroll
    for (int off = 8; off > 0; off >>= 1)
#pragma unroll
      for (int u = 0; u < 8; ++u)
        dd[u] += __shfl_xor(dd[u], off, 16);

    if (lg == 0) {
#pragma unroll
      for (int u = 0; u < 8; ++u) {
        uint64 bits = (uint64)__double_as_longlong(dd[u]);   // d >= 0: order-preserving
        sK64[grp][q0 + u] = (bits & ~2047ULL) | (uint64)jj[u];
      }
    }
  }
  __syncthreads();

  if (t < 16) {
    uint64 bl[KK];
#pragma unroll
    for (int s = 0; s < KK; ++s) bl[s] = ~0ULL;
    for (int q = 0; q < 80; ++q) {
      uint64 c = sK64[t][q];
      if (c < bl[KK - 1]) {
        uint64 cur = c;
#pragma unroll
        for (int s = 0; s < KK; ++s) {
          uint64 lo = bl[s] < cur ? bl[s] : cur;
          cur = bl[s] < cur ? cur : bl[s];
          bl[s] = lo;
        }
      }
    }
    size_t base = ((size_t)(b * NN + i0 + t)) * KK;
#pragma unroll
    for (int s = 0; s < KK; ++s) idxout[base + s] = (int)(bl[s] & 2047ULL);
  }
}

// ---------------------------------------------------------------- K2: edge MLP + max-agg (unchanged)
__launch_bounds__(256, 2)
__global__ void k_mlp(const float* __restrict__ x, const int* __restrict__ idx,
                      const float* __restrict__ w1, const float* __restrict__ b1,
                      const float* __restrict__ w2, const float* __restrict__ b2,
                      const float* __restrict__ w3, const float* __restrict__ b3,
                      float* __restrict__ agg) {
  const int b  = blockIdx.y;
  const int i0 = blockIdx.x * 4;
  const int t  = threadIdx.x;
  const int l  = t & 63, wv = t >> 6;
  const int la = l & 15, quad = l >> 4;

  __shared__ __align__(16) char sm[79936];
  ushortT (*sW1)[132] = (ushortT(*)[132])(sm + 0);
  ushortT (*sW2)[68]  = (ushortT(*)[68])(sm + 16896);
  ushortT (*sW3)[68]  = (ushortT(*)[68])(sm + 25600);
  ushortT (*sXi)[68]  = (ushortT(*)[68])(sm + 34304);
  ushortT (*sDH)[68]  = (ushortT(*)[68])(sm + 45184);
  ushortT (*sDL)[68]  = (ushortT(*)[68])(sm + 56064);
  ushortT (*sH1)[68]  = (ushortT(*)[68])(sm + 66944);
  uint32*  sAgg       = (uint32*)(sm + 77824);
  float*   sB1        = (float*)(sm + 78848);
  float*   sB2        = (float*)(sm + 79104);
  float*   sB3        = (float*)(sm + 79360);
  int*     sJ         = (int*)(sm + 79616);

  for (int e = t; e < 8192; e += 256) {
    int k = e >> 6, n = e & 63;
    sW1[n][k] = f2bf(w1[e]);
  }
  for (int e = t; e < 4096; e += 256) {
    int k = e >> 6, n = e & 63;
    sW2[n][k] = f2bf(w2[e]);
    sW3[n][k] = f2bf(w3[e]);
  }
  if (t < 64) { sB1[t] = b1[t]; sB2[t] = b2[t]; sB3[t] = b3[t]; }
  if (t < 80) {
    int p = t / 20, kk = t - p * 20;
    int v = idx[((size_t)(b * NN + i0 + p)) * KK + kk];
    v = v < 0 ? 0 : (v > (NN - 1) ? (NN - 1) : v);
    sJ[t] = v;
  }
  sAgg[t] = 0u;
  __syncthreads();

  const float* xb = x + ((size_t)b * NN) * CC;
  for (int e = t; e < 1280; e += 256) {
    int r = e >> 4, c4g = e & 15, c4 = c4g * 4;
    int p = r / 20;
    float4 vi = ((const float4*)(xb + (size_t)(i0 + p) * CC))[c4g];
    float4 vj = ((const float4*)(xb + (size_t)sJ[r] * CC))[c4g];
    short4v hi, dh, dl;
    ushortT hh, ll;
    hi.x = (short)f2bf(vi.x); hi.y = (short)f2bf(vi.y);
    hi.z = (short)f2bf(vi.z); hi.w = (short)f2bf(vi.w);
    split2(vj.x - vi.x, hh, ll); dh.x = (short)hh; dl.x = (short)ll;
    split2(vj.y - vi.y, hh, ll); dh.y = (short)hh; dl.y = (short)ll;
    split2(vj.z - vi.z, hh, ll); dh.z = (short)hh; dl.z = (short)ll;
    split2(vj.w - vi.w, hh, ll); dh.w = (short)hh; dl.w = (short)ll;
    *(short4v*)&sXi[r][c4] = hi;
    *(short4v*)&sDH[r][c4] = dh;
    *(short4v*)&sDL[r][c4] = dl;
  }
  __syncthreads();

  const int c = wv * 16 + la;

  // ---- layer 1
  {
    short8 bA[2], bB[2];
#pragma unroll
    for (int ks = 0; ks < 2; ++ks) {
      bA[ks] = ld8(&sW1[c][ks * 32 + quad * 8]);
      bB[ks] = ld8(&sW1[c][64 + ks * 32 + quad * 8]);
    }
#pragma unroll
    for (int m5 = 0; m5 < 5; ++m5) {
      floatx4 a = (floatx4){0.f, 0.f, 0.f, 0.f};
#pragma unroll
      for (int ks = 0; ks < 2; ++ks) {
        int kof = ks * 32 + quad * 8;
        short8 aXi = ld8(&sXi[m5 * 16 + la][kof]);
        short8 aDH = ld8(&sDH[m5 * 16 + la][kof]);
        short8 aDL = ld8(&sDL[m5 * 16 + la][kof]);
        a = __builtin_amdgcn_mfma_f32_16x16x32_bf16(aXi, bA[ks], a, 0, 0, 0);
        a = __builtin_amdgcn_mfma_f32_16x16x32_bf16(aDH, bB[ks], a, 0, 0, 0);
        a = __builtin_amdgcn_mfma_f32_16x16x32_bf16(aDL, bB[ks], a, 0, 0, 0);
      }
      float bia = sB1[c];
#pragma unroll
      for (int rg = 0; rg < 4; ++rg) {
        int r = m5 * 16 + quad * 4 + rg;
        sH1[r][c] = f2bf(fmaxf(a[rg] + bia, 0.f));
      }
    }
  }
  __syncthreads();

  // ---- layer 2
  ushortT (*sH2)[68] = sXi;
  {
    short8 bf[2];
#pragma unroll
    for (int ks = 0; ks < 2; ++ks)
      bf[ks] = ld8(&sW2[c][ks * 32 + quad * 8]);
#pragma unroll
    for (int m5 = 0; m5 < 5; ++m5) {
      floatx4 a = (floatx4){0.f, 0.f, 0.f, 0.f};
#pragma unroll
      for (int ks = 0; ks < 2; ++ks) {
        short8 aH = ld8(&sH1[m5 * 16 + la][ks * 32 + quad * 8]);
        a = __builtin_amdgcn_mfma_f32_16x16x32_bf16(aH, bf[ks], a, 0, 0, 0);
      }
      float bia = sB2[c];
#pragma unroll
      for (int rg = 0; rg < 4; ++rg) {
        int r = m5 * 16 + quad * 4 + rg;
        sH2[r][c] = f2bf(fmaxf(a[rg] + bia, 0.f));
      }
    }
  }
  __syncthreads();

  // ---- layer 3
  {
    short8 bf[2];
#pragma unroll
    for (int ks = 0; ks < 2; ++ks)
      bf[ks] = ld8(&sW3[c][ks * 32 + quad * 8]);
#pragma unroll
    for (int m5 = 0; m5 < 5; ++m5) {
      floatx4 a = (floatx4){0.f, 0.f, 0.f, 0.f};
#pragma unroll
      for (int ks = 0; ks < 2; ++ks) {
        short8 aH = ld8(&sH2[m5 * 16 + la][ks * 32 + quad * 8]);
        a = __builtin_amdgcn_mfma_f32_16x16x32_bf16(aH, bf[ks], a, 0, 0, 0);
      }
      float bia = sB3[c];
#pragma unroll
      for (int rg = 0; rg < 4; ++rg) {
        int r = m5 * 16 + quad * 4 + rg;
        int p = r / 20;
        atomicMax(&sAgg[p * 64 + c], fmap(a[rg] + bia));
      }
    }
  }
  __syncthreads();

  {
    int p = t >> 6, cc = t & 63;
    agg[((size_t)(b * NN + i0 + p)) * CC + cc] = funmap(sAgg[t]);
  }
}

// ---------------------------------------------------------------- K3: SE (f32)
__global__ void k_se(const float* __restrict__ agg, const float* __restrict__ sew1,
                     const float* __restrict__ sew2, float* __restrict__ y) {
  int b = blockIdx.x, t = threadIdx.x;
  int c = t & 63, q = t >> 6;
  __shared__ float part[4][64];
  __shared__ float sv[64];
  __shared__ float hid[4];
  const float* ab = agg + ((size_t)b * NN) * CC;
  float s = 0.f;
  for (int n = q * 512; n < q * 512 + 512; ++n) s += ab[(size_t)n * CC + c];
  part[q][c] = s;
  __syncthreads();
  if (t < 64) sv[t] = (part[0][t] + part[1][t] + part[2][t] + part[3][t]) * (1.f / 2048.f);
  __syncthreads();
  if (t < 4) {
    float a = 0.f;
    for (int cc = 0; cc < 64; ++cc) a += sv[cc] * sew1[cc * 4 + t];
    hid[t] = fmaxf(a, 0.f);
  }
  __syncthreads();
  if (t < 64) {
    float a = 0.f;
#pragma unroll
    for (int h = 0; h < 4; ++h) a += hid[h] * sew2[h * 64 + t];
    y[b * 64 + t] = 1.f / (1.f + expf(-a));
  }
}

// ---------------------------------------------------------------- K4: per-point stats (f32)
__global__ void k_stats(const float* __restrict__ agg, const float* __restrict__ y,
                        float* __restrict__ ycat) {
  int t = threadIdx.x;
  int gid = blockIdx.x * 4 + (t >> 6);
  int l = t & 63;
  int b = gid >> 11, i = gid & 2047;
  float v = agg[(size_t)gid * CC + l] * y[b * 64 + l];
  float s = v, mx = v;
#pragma unroll
  for (int off = 32; off > 0; off >>= 1) {
    s += __shfl_xor(s, off);
    mx = fmaxf(mx, __shfl_xor(mx, off));
  }
  if (l == 0) {
    ycat[b * 2 * NN + i] = s * (1.f / 64.f);
    ycat[b * 2 * NN + NN + i] = mx;
  }
}

// ---------------------------------------------------------------- K5: conv7 att + add (f32 out)
__global__ void k_final(const float* __restrict__ agg, const float* __restrict__ y,
                        const float* __restrict__ ycat, const float* __restrict__ saw,
                        const float* __restrict__ x, float* __restrict__ out) {
  int e = blockIdx.x * 256 + threadIdx.x;
  int ifl = e >> 6, c = e & 63;
  int b = ifl >> 11, i = ifl & 2047;
  float a = 0.f;
#pragma unroll
  for (int w = 0; w < 7; ++w) {
    int ii = i + w - 3;
    if (ii >= 0 && ii < NN) {
      a += ycat[b * 2 * NN + ii] * saw[w];
      a += ycat[b * 2 * NN + NN + ii] * saw[7 + w];
    }
  }
  float att = 1.f / (1.f + expf(-a));
  out[e] = agg[(size_t)ifl * CC + c] * y[b * 64 + c] * att + x[(size_t)e];
}

// ----------------------------------------------------------------
extern "C" void kernel_launch(void* const* d_in, const int* in_sizes, int n_in,
                              void* d_out, int out_size, void* d_ws, size_t ws_size,
                              hipStream_t stream) {
  const float* x    = (const float*)d_in[0];
  const float* w1   = (const float*)d_in[3];
  const float* b1   = (const float*)d_in[4];
  const float* w2   = (const float*)d_in[5];
  const float* b2   = (const float*)d_in[6];
  const float* w3   = (const float*)d_in[7];
  const float* b3   = (const float*)d_in[8];
  const float* sew1 = (const float*)d_in[9];
  const float* sew2 = (const float*)d_in[10];
  const float* saw  = (const float*)d_in[11];
  float* out = (float*)d_out;

  char* ws = (char*)d_ws;
  float*   sq   = (float*)  (ws);                          // 131072 B
  int*     idx  = (int*)    (ws + 131072);                 // 2621440 B
  ushortT* cand = (ushortT*)(ws + 2752512);                // 5242880 B (32768*80 u16)
  float*   agg  = (float*)  (ws + 2752512);                // 8388608 B (aliases cand; cand
                                                           // consumed before k_mlp writes)
  float*   y    = (float*)  (ws + 11141120);               // 4096 B
  float*   ycat = (float*)  (ws + 11145216);               // 262144 B -> total 11407360 B

  // bf16 image of x lives in d_out (4 MB of its 8 MB) until k_final overwrites it.
  ushortT* xbf = (ushortT*)d_out;

  k_sq    <<<128,            256, 0, stream>>>(x, sq, xbf);
  k_knn   <<<dim3(32, 16),   256, 0, stream>>>(xbf, sq, cand);
  k_rerank<<<dim3(128, 16),  256, 0, stream>>>(x, cand, idx);
  k_mlp   <<<dim3(512, 16),  256, 0, stream>>>(x, idx, w1, b1, w2, b2, w3, b3, agg);
  k_se    <<<16,             256, 0, stream>>>(agg, sew1, sew2, y);
  k_stats <<<8192,           256, 0, stream>>>(agg, y, ycat);
  k_final <<<8192,           256, 0, stream>>>(agg, y, ycat, saw, x, out);
}